// Round 1
// baseline (2287.202 us; speedup 1.0000x reference)
//
#include <hip/hip_runtime.h>
#include <stdint.h>

typedef float f32x4 __attribute__((ext_vector_type(4)));
typedef short s16x8 __attribute__((ext_vector_type(8)));
typedef unsigned long long u64;

__device__ __forceinline__ unsigned short f2bf(float f) {
  union { float f; unsigned u; } v; v.f = f;
  unsigned u = v.u;
  return (unsigned short)((u + 0x7FFFu + ((u >> 16) & 1u)) >> 16);
}
__device__ __forceinline__ float bf2f(unsigned short b) {
  union { unsigned u; float f; } v; v.u = ((unsigned)b) << 16; return v.f;
}

// ---------------- conv1: 3x3, 512->512, 64x64, SAME, +bias, relu --------------
// out y layout: [px=4096][oc=512] fp32
#define ICC 16
__global__ __launch_bounds__(256) void k_conv1(const float* __restrict__ fm,
                                               const float* __restrict__ w,
                                               const float* __restrict__ bias,
                                               float* __restrict__ y) {
  __shared__ float Ws[ICC * 9 * 68];
  __shared__ float Xs[ICC * 100];
  int bid = blockIdx.x;
  int ocg = bid & 7, sp = bid >> 3;
  int h0 = (sp >> 3) * 8, w0 = (sp & 7) * 8;
  int oc0 = ocg * 64;
  int t = threadIdx.x;
  int ocq = t >> 4, pxq = t & 15;
  int prow = pxq >> 1, pcolb = (pxq & 1) * 4;
  float acc[4][4] = {};
  for (int c0 = 0; c0 < 512; c0 += ICC) {
    for (int idx = t; idx < ICC * 100; idx += 256) {
      int ic = idx / 100; int rem = idx - ic * 100;
      int yy = rem / 10; int xx = rem - yy * 10;
      int gy = h0 + yy - 1, gx = w0 + xx - 1;
      float v = 0.f;
      if ((unsigned)gy < 64u && (unsigned)gx < 64u) v = fm[(c0 + ic) * 4096 + gy * 64 + gx];
      Xs[idx] = v;
    }
    for (int idx = t; idx < 64 * ICC * 9; idx += 256) {
      int oc = idx / (ICC * 9); int r = idx - oc * (ICC * 9);
      Ws[r * 68 + oc] = w[(oc0 + oc) * 4608 + c0 * 9 + r];
    }
    __syncthreads();
    for (int ic = 0; ic < ICC; ic++) {
      #pragma unroll
      for (int k = 0; k < 9; k++) {
        const int kh = k / 3, kw = k - kh * 3;
        f32x4 wv = *(const f32x4*)&Ws[(ic * 9 + k) * 68 + ocq * 4];
        const float* xp = &Xs[ic * 100 + (prow + kh) * 10 + pcolb + kw];
        float x0 = xp[0], x1 = xp[1], x2 = xp[2], x3 = xp[3];
        acc[0][0] += wv.x * x0; acc[0][1] += wv.x * x1; acc[0][2] += wv.x * x2; acc[0][3] += wv.x * x3;
        acc[1][0] += wv.y * x0; acc[1][1] += wv.y * x1; acc[1][2] += wv.y * x2; acc[1][3] += wv.y * x3;
        acc[2][0] += wv.z * x0; acc[2][1] += wv.z * x1; acc[2][2] += wv.z * x2; acc[2][3] += wv.z * x3;
        acc[3][0] += wv.w * x0; acc[3][1] += wv.w * x1; acc[3][2] += wv.w * x2; acc[3][3] += wv.w * x3;
      }
    }
    __syncthreads();
  }
  float b0 = bias[oc0 + ocq * 4 + 0], b1 = bias[oc0 + ocq * 4 + 1];
  float b2 = bias[oc0 + ocq * 4 + 2], b3 = bias[oc0 + ocq * 4 + 3];
  #pragma unroll
  for (int j = 0; j < 4; j++) {
    int px = (h0 + prow) * 64 + (w0 + pcolb + j);
    f32x4 v;
    v.x = fmaxf(acc[0][j] + b0, 0.f);
    v.y = fmaxf(acc[1][j] + b1, 0.f);
    v.z = fmaxf(acc[2][j] + b2, 0.f);
    v.w = fmaxf(acc[3][j] + b3, 0.f);
    *(f32x4*)&y[(u64)px * 512 + oc0 + ocq * 4] = v;
  }
}

// --------------- 1x1 convs: scores (sigmoid) + deltas ------------------------
__global__ __launch_bounds__(256) void k_rpn1x1(const float* __restrict__ y,
                                                const float* __restrict__ cw, const float* __restrict__ cb,
                                                const float* __restrict__ bw, const float* __restrict__ bb,
                                                float* __restrict__ out_s, float* __restrict__ out_d) {
  __shared__ float Ys[16 * 516];
  int px0 = blockIdx.x * 16;
  int t = threadIdx.x;
  for (int c = t; c < 16 * 128; c += 256) {
    int p = c >> 7, seg = c & 127;
    f32x4 v = *(const f32x4*)&y[(u64)(px0 + p) * 512 + seg * 4];
    *(f32x4*)&Ys[p * 516 + seg * 4] = v;
  }
  __syncthreads();
  int px = t & 15, og = t >> 4;
  const float* yr = &Ys[px * 516];
  for (int n = og; n < 45; n += 16) {
    const float* wr = (n < 9) ? &cw[n * 512] : &bw[(n - 9) * 512];
    float acc = 0.f;
    for (int k = 0; k < 512; k += 4) {
      f32x4 wv = *(const f32x4*)&wr[k];
      acc += wv.x * yr[k] + wv.y * yr[k + 1] + wv.z * yr[k + 2] + wv.w * yr[k + 3];
    }
    int gpx = px0 + px;
    if (n < 9) {
      float s = acc + cb[n];
      out_s[gpx * 9 + n] = 1.f / (1.f + expf(-s));
    } else {
      out_d[gpx * 36 + (n - 9)] = acc + bb[n - 9];
    }
  }
}

// --------------- box decode + sort keys --------------------------------------
__global__ void k_decode(const float* __restrict__ sc, const float* __restrict__ dl,
                         const float* __restrict__ amap,
                         float* __restrict__ boxes, u64* __restrict__ keys) {
  int i = blockIdx.x * 256 + threadIdx.x;
  if (i >= 65536) return;
  if (i < 36864) {
    int px = i / 9, a = i - px * 9;
    const float* A = &amap[i * 4];
    const float* D = &dl[px * 36 + a * 4];
    float cy = A[0] + D[0] * A[2];
    float cx = A[1] + D[1] * A[3];
    float hh = A[2] * expf(D[2]);
    float ww = A[3] * expf(D[3]);
    float y1 = fminf(fmaxf(cy - 0.5f * hh, 0.f), 1023.f);
    float x1 = fminf(fmaxf(cx - 0.5f * ww, 0.f), 1023.f);
    float y2 = fminf(fmaxf(cy + 0.5f * hh, 0.f), 1023.f);
    float x2 = fminf(fmaxf(cx + 0.5f * ww, 0.f), 1023.f);
    f32x4 v; v.x = y1; v.y = x1; v.z = y2; v.w = x2;
    *(f32x4*)&boxes[i * 4] = v;
    unsigned bits = __float_as_uint(sc[i]);
    u64 key = ((u64)bits << 16) | (u64)(0xFFFFu - (unsigned)i);
    keys[i] = ~key;  // ascending sort of ~key == descending by (score, -idx)
  } else {
    keys[i] = ~0ull;
  }
}

// --------------- bitonic sort of 65536 u64 keys (ascending) ------------------
__global__ __launch_bounds__(1024) void k_sort_local(u64* __restrict__ keys) {
  __shared__ u64 S[8192];
  int base = blockIdx.x * 8192;
  for (int i = threadIdx.x; i < 8192; i += 1024) S[i] = keys[base + i];
  __syncthreads();
  for (int k = 2; k <= 8192; k <<= 1) {
    for (int j = k >> 1; j > 0; j >>= 1) {
      for (int p = threadIdx.x; p < 4096; p += 1024) {
        int i = ((p & ~(j - 1)) << 1) | (p & (j - 1));
        int ix = i | j;
        bool up = (((base + i) & k) == 0);
        u64 a = S[i], c = S[ix];
        if ((a > c) == up) { S[i] = c; S[ix] = a; }
      }
      __syncthreads();
    }
  }
  for (int i = threadIdx.x; i < 8192; i += 1024) keys[base + i] = S[i];
}

__global__ void k_sort_global(u64* __restrict__ keys, int k, int j) {
  int p = blockIdx.x * 256 + threadIdx.x;
  int i = ((p & ~(j - 1)) << 1) | (p & (j - 1));
  int ix = i | j;
  bool up = ((i & k) == 0);
  u64 a = keys[i], c = keys[ix];
  if ((a > c) == up) { keys[i] = c; keys[ix] = a; }
}

__global__ __launch_bounds__(1024) void k_sort_merge(u64* __restrict__ keys, int k) {
  __shared__ u64 S[8192];
  int base = blockIdx.x * 8192;
  for (int i = threadIdx.x; i < 8192; i += 1024) S[i] = keys[base + i];
  __syncthreads();
  for (int j = 4096; j > 0; j >>= 1) {
    for (int p = threadIdx.x; p < 4096; p += 1024) {
      int i = ((p & ~(j - 1)) << 1) | (p & (j - 1));
      int ix = i | j;
      bool up = (((base + i) & k) == 0);
      u64 a = S[i], c = S[ix];
      if ((a > c) == up) { S[i] = c; S[ix] = a; }
    }
    __syncthreads();
  }
  for (int i = threadIdx.x; i < 8192; i += 1024) keys[base + i] = S[i];
}

__global__ void k_gather_sorted(const u64* __restrict__ keys, const float* __restrict__ boxes,
                                float* __restrict__ bx) {
  int p = blockIdx.x * 256 + threadIdx.x;
  if (p >= 6000) return;
  u64 key = ~keys[p];
  int idx = 0xFFFF - (int)(key & 0xFFFFull);
  *(f32x4*)&bx[p * 4] = *(const f32x4*)&boxes[idx * 4];
}

// --------------- NMS: suppression bitmask + sequential scan ------------------
__global__ __launch_bounds__(128) void k_nms_mask(const float* __restrict__ bx, u64* __restrict__ mask) {
  int i = blockIdx.x;
  int w = threadIdx.x;
  if (w >= 94) return;
  f32x4 bi = *(const f32x4*)&bx[i * 4];
  float ai = (bi.z - bi.x) * (bi.w - bi.y);
  u64 m = 0;
  int j0 = w * 64;
  for (int b = 0; b < 64; b++) {
    int j = j0 + b;
    if (j >= 6000) break;
    if (j <= i) continue;
    f32x4 bj = *(const f32x4*)&bx[j * 4];
    float yy1 = fmaxf(bi.x, bj.x), xx1 = fmaxf(bi.y, bj.y);
    float yy2 = fminf(bi.z, bj.z), xx2 = fminf(bi.w, bj.w);
    float inter = fmaxf(yy2 - yy1, 0.f) * fmaxf(xx2 - xx1, 0.f);
    float aj = (bj.z - bj.x) * (bj.w - bj.y);
    float iou = inter / (ai + aj - inter + 1e-8f);
    if (iou > 0.7f) m |= (1ull << b);
  }
  mask[i * 94 + w] = m;
}

__global__ __launch_bounds__(64) void k_nms_scan(const u64* __restrict__ mask, int* __restrict__ sel) {
  int lane = threadIdx.x;
  u64 rem0 = 0, rem1 = 0;
  for (int c0 = 0; c0 < 6000; c0 += 16) {
    u64 r0[16], r1[16];
    #pragma unroll
    for (int r = 0; r < 16; r++) {
      r0[r] = mask[(c0 + r) * 94 + lane];
      r1[r] = (lane < 30) ? mask[(c0 + r) * 94 + 64 + lane] : 0ull;
    }
    #pragma unroll
    for (int r = 0; r < 16; r++) {
      int i = c0 + r;
      int wi = i >> 6, bi = i & 63;
      u64 wv = (wi < 64) ? __shfl(rem0, wi, 64) : __shfl(rem1, wi - 64, 64);
      if (!((wv >> bi) & 1ull)) { rem0 |= r0[r]; rem1 |= r1[r]; }
    }
  }
  __shared__ u64 rem[94];
  __shared__ u64 keep[94];
  __shared__ int pref[96];
  __shared__ int pref2[96];
  rem[lane] = rem0;
  if (lane < 30) rem[64 + lane] = rem1;
  __syncthreads();
  for (int w = lane; w < 94; w += 64) {
    u64 valid = (w == 93) ? ((1ull << 48) - 1ull) : ~0ull;
    keep[w] = (~rem[w]) & valid;
    rem[w] &= valid;
  }
  __syncthreads();
  if (lane == 0) {
    int tot = 0;
    for (int w = 0; w < 94; w++) { pref[w] = tot; tot += __popcll(keep[w]); }
    pref[94] = tot;
    int tot2 = tot;
    for (int w = 0; w < 94; w++) { pref2[w] = tot2; tot2 += __popcll(rem[w]); }
  }
  __syncthreads();
  int U = pref[94];
  for (int w = lane; w < 94; w += 64) {
    u64 kb = keep[w];
    int rank = pref[w];
    while (kb) {
      int b = __ffsll((unsigned long long)kb) - 1;
      if (rank < 300) sel[rank] = w * 64 + b;
      rank++;
      kb &= kb - 1;
    }
    if (U < 300) {
      u64 sb = rem[w];
      int rank2 = pref2[w];
      while (sb) {
        int b = __ffsll((unsigned long long)sb) - 1;
        if (rank2 < 300) sel[rank2] = w * 64 + b;
        rank2++;
        sb &= sb - 1;
      }
    }
  }
}

__global__ void k_gather_prop(const int* __restrict__ sel, const float* __restrict__ bx,
                              float* __restrict__ out_p, float* __restrict__ rois) {
  int r = blockIdx.x * 64 + threadIdx.x;
  if (r >= 300) return;
  int p = sel[r];
  float y1 = bx[p * 4 + 0], x1 = bx[p * 4 + 1], y2 = bx[p * 4 + 2], x2 = bx[p * 4 + 3];
  out_p[r * 4 + 0] = y1; out_p[r * 4 + 1] = x1; out_p[r * 4 + 2] = y2; out_p[r * 4 + 3] = x2;
  rois[r * 4 + 0] = x1; rois[r * 4 + 1] = y1; rois[r * 4 + 2] = x2; rois[r * 4 + 3] = y2;
}

// --------------- ROI max-pool 7x7 (exact ref semantics), out bf16 ------------
__global__ __launch_bounds__(256) void k_roipool(const float* __restrict__ fm,
                                                 const float* __restrict__ rois,
                                                 unsigned short* __restrict__ pooled) {
  int roi = blockIdx.x;
  __shared__ int hs[7], he[7], wls[7], wle[7];
  if (threadIdx.x < 28) {
    int kind = threadIdx.x / 7, p = threadIdx.x - kind * 7;
    float x1 = rintf(rois[roi * 4 + 0] * 0.0625f);
    float y1 = rintf(rois[roi * 4 + 1] * 0.0625f);
    float x2 = rintf(rois[roi * 4 + 2] * 0.0625f);
    float y2 = rintf(rois[roi * 4 + 3] * 0.0625f);
    float rw = fmaxf(x2 - x1 + 1.f, 1.f), rh = fmaxf(y2 - y1 + 1.f, 1.f);
    float bh = rh / 7.f, bw = rw / 7.f;
    float fp = (float)p;
    if (kind == 0) hs[p]  = (int)fminf(fmaxf(floorf(fp * bh) + y1, 0.f), 64.f);
    if (kind == 1) he[p]  = (int)fminf(fmaxf(ceilf((fp + 1.f) * bh) + y1, 0.f), 64.f);
    if (kind == 2) wls[p] = (int)fminf(fmaxf(floorf(fp * bw) + x1, 0.f), 64.f);
    if (kind == 3) wle[p] = (int)fminf(fmaxf(ceilf((fp + 1.f) * bw) + x1, 0.f), 64.f);
  }
  __syncthreads();
  for (int o = threadIdx.x; o < 512 * 49; o += 256) {
    int c = o / 49; int cell = o - c * 49;
    int ph = cell / 7, pw = cell - ph * 7;
    int y0 = hs[ph], y1e = he[ph], x0 = wls[pw], x1e = wle[pw];
    bool any = (y1e > y0) && (x1e > x0);
    float m = -1e30f;
    const float* base = &fm[c * 4096];
    for (int yy = y0; yy < y1e; yy++)
      for (int xx = x0; xx < x1e; xx++)
        m = fmaxf(m, base[yy * 64 + xx]);
    pooled[(u64)roi * 25088 + o] = f2bf(any ? m : 0.f);
  }
}

// --------------- big GEMM: C[320][N] += A_bf16[320][K] * B_f32[N][K]^T --------
// grid (N/128, S); K-split via atomicAdd into pre-zeroed Cpre.
__global__ __launch_bounds__(512) void k_gemm(const unsigned short* __restrict__ A,
                                              const float* __restrict__ B,
                                              float* __restrict__ Cpre,
                                              int K, int Kslice, int N) {
  __shared__ unsigned short As[320 * 40];
  int n0 = blockIdx.x * 128;
  int s = blockIdx.y;
  int t = threadIdx.x;
  int wave = t >> 6, lane = t & 63;
  int mg = wave & 1, ng = wave >> 1;
  int m0 = mg * 160;
  int n0w = n0 + ng * 32;
  int lr = lane & 15, lk = lane >> 4;
  f32x4 acc[10][2];
  #pragma unroll
  for (int mt = 0; mt < 10; mt++)
    for (int nt = 0; nt < 2; nt++) { acc[mt][nt].x = 0; acc[mt][nt].y = 0; acc[mt][nt].z = 0; acc[mt][nt].w = 0; }
  int kbeg = s * Kslice, kend = kbeg + Kslice;
  for (int k0 = kbeg; k0 < kend; k0 += 32) {
    for (int c = t; c < 1280; c += 512) {
      int m = c >> 2, seg = (c & 3) * 8;
      *(uint4*)&As[m * 40 + seg] = *(const uint4*)&A[(u64)m * K + k0 + seg];
    }
    __syncthreads();
    s16x8 bfrag[2];
    #pragma unroll
    for (int nt = 0; nt < 2; nt++) {
      const float* bp = &B[(u64)(n0w + nt * 16 + lr) * K + k0 + lk * 8];
      f32x4 b0 = *(const f32x4*)bp;
      f32x4 b1 = *(const f32x4*)(bp + 4);
      s16x8 f;
      f[0] = (short)f2bf(b0.x); f[1] = (short)f2bf(b0.y); f[2] = (short)f2bf(b0.z); f[3] = (short)f2bf(b0.w);
      f[4] = (short)f2bf(b1.x); f[5] = (short)f2bf(b1.y); f[6] = (short)f2bf(b1.z); f[7] = (short)f2bf(b1.w);
      bfrag[nt] = f;
    }
    #pragma unroll
    for (int mt = 0; mt < 10; mt++) {
      s16x8 afrag = *(const s16x8*)&As[(m0 + mt * 16 + lr) * 40 + lk * 8];
      acc[mt][0] = __builtin_amdgcn_mfma_f32_16x16x32_bf16(afrag, bfrag[0], acc[mt][0], 0, 0, 0);
      acc[mt][1] = __builtin_amdgcn_mfma_f32_16x16x32_bf16(afrag, bfrag[1], acc[mt][1], 0, 0, 0);
    }
    __syncthreads();
  }
  #pragma unroll
  for (int mt = 0; mt < 10; mt++)
    for (int nt = 0; nt < 2; nt++)
      for (int r = 0; r < 4; r++) {
        int m = m0 + mt * 16 + lk * 4 + r;
        int n = n0w + nt * 16 + lr;
        atomicAdd(&Cpre[(u64)m * N + n], acc[mt][nt][r]);
      }
}

__global__ void k_bias_relu_bf(const float* __restrict__ pre, const float* __restrict__ bias,
                               unsigned short* __restrict__ outb) {
  int i = blockIdx.x * 256 + threadIdx.x;  // 320*4096 total
  float v = pre[i] + bias[i & 4095];
  outb[i] = f2bf(fmaxf(v, 0.f));
}

// --------------- heads: cls softmax + reg ------------------------------------
__global__ __launch_bounds__(128) void k_head(const unsigned short* __restrict__ h2,
                                              const float* __restrict__ cw, const float* __restrict__ cb,
                                              const float* __restrict__ rw, const float* __restrict__ rb,
                                              float* __restrict__ out_cls, float* __restrict__ out_reg) {
  __shared__ float Hs[4096];
  __shared__ float logits[101];
  __shared__ float es[21];
  int r = blockIdx.x, t = threadIdx.x;
  for (int c = t; c < 512; c += 128) {
    uint4 raw = *(const uint4*)&h2[(u64)r * 4096 + c * 8];
    unsigned short* sp = (unsigned short*)&raw;
    #pragma unroll
    for (int q = 0; q < 8; q++) Hs[c * 8 + q] = bf2f(sp[q]);
  }
  __syncthreads();
  for (int n = t; n < 101; n += 128) {
    const float* wrow = (n < 21) ? &cw[n * 4096] : &rw[(n - 21) * 4096];
    float acc = 0.f;
    for (int k = 0; k < 4096; k += 4) {
      f32x4 wv = *(const f32x4*)&wrow[k];
      acc += wv.x * Hs[k] + wv.y * Hs[k + 1] + wv.z * Hs[k + 2] + wv.w * Hs[k + 3];
    }
    acc += (n < 21) ? cb[n] : rb[n - 21];
    logits[n] = acc;
  }
  __syncthreads();
  if (t < 21) {
    float mx = logits[0];
    for (int q = 1; q < 21; q++) mx = fmaxf(mx, logits[q]);
    es[t] = expf(logits[t] - mx);
  }
  __syncthreads();
  if (t < 21) {
    float sum = 0.f;
    for (int q = 0; q < 21; q++) sum += es[q];
    out_cls[r * 21 + t] = es[t] / sum;
  }
  if (t >= 21 && t < 101) out_reg[r * 80 + (t - 21)] = logits[t];
}

// ------------------------------- launcher ------------------------------------
extern "C" void kernel_launch(void* const* d_in, const int* in_sizes, int n_in,
                              void* d_out, int out_size, void* d_ws, size_t ws_size,
                              hipStream_t stream) {
  (void)in_sizes; (void)n_in; (void)out_size; (void)ws_size;
  const float* fm     = (const float*)d_in[0];
  const float* amap   = (const float*)d_in[1];
  const float* conv_w = (const float*)d_in[3];
  const float* conv_b = (const float*)d_in[4];
  const float* cls_w  = (const float*)d_in[5];
  const float* cls_b  = (const float*)d_in[6];
  const float* box_w  = (const float*)d_in[7];
  const float* box_b  = (const float*)d_in[8];
  const float* fc1_w  = (const float*)d_in[9];
  const float* fc1_b  = (const float*)d_in[10];
  const float* fc2_w  = (const float*)d_in[11];
  const float* fc2_b  = (const float*)d_in[12];
  const float* cw     = (const float*)d_in[13];
  const float* cbias  = (const float*)d_in[14];
  const float* rw     = (const float*)d_in[15];
  const float* rbias  = (const float*)d_in[16];

  float* out_s = (float*)d_out;           // 36864
  float* out_d = out_s + 36864;           // 147456
  float* out_p = out_d + 147456;          // 1200
  float* out_c = out_p + 1200;            // 6300
  float* out_r = out_c + 6300;            // 24000

  char* ws = (char*)d_ws;
  // phase-1 overlay region [0, ~15.05MB) is later reused by `pooled` (rows 300+ pad
  // live at [15,052,800, 16,056,320) and are untouched by phase 1).
  unsigned short* pooled = (unsigned short*)(ws + 0);          // 320*25088*2 = 16,056,320
  u64*   mask  = (u64*)  (ws + 0);                             // 6000*94*8 = 4,512,000
  float* y     = (float*)(ws + 4718592);                       // 4096*512*4 = 8,388,608
  float* boxes = (float*)(ws + 13107200);                      // 36864*4*4 = 589,824
  u64*   keys  = (u64*)  (ws + 13697024);                      // 65536*8 = 524,288 (ends 14,221,312)
  float* bx    = (float*)(ws + 16056320);                      // 6000*4*4 = 96,000
  int*   sel   = (int*)  (ws + 16152320);                      // 300*4 (pad 1280)
  float* rois  = (float*)(ws + 16153600);                      // 300*4*4 = 4,800
  float* h1pre = (float*)(ws + 16158400);                      // 320*4096*4 = 5,242,880
  unsigned short* h1bf = (unsigned short*)(ws + 21401280);     // 320*4096*2 = 2,621,440
  float* h2pre = (float*)(ws + 24022720);                      // 5,242,880
  unsigned short* h2bf = (unsigned short*)(ws + 29265600);     // 2,621,440  (end ~31.9MB)

  hipMemsetAsync(h1pre, 0, (size_t)320 * 4096 * 4, stream);
  hipMemsetAsync(h2pre, 0, (size_t)320 * 4096 * 4, stream);
  hipMemsetAsync((char*)pooled + (size_t)300 * 25088 * 2, 0, (size_t)20 * 25088 * 2, stream);

  k_conv1<<<512, 256, 0, stream>>>(fm, conv_w, conv_b, y);
  k_rpn1x1<<<256, 256, 0, stream>>>(y, cls_w, cls_b, box_w, box_b, out_s, out_d);
  k_decode<<<256, 256, 0, stream>>>(out_s, out_d, amap, boxes, keys);

  k_sort_local<<<8, 1024, 0, stream>>>(keys);
  for (int k = 16384; k <= 65536; k <<= 1) {
    for (int j = k >> 1; j >= 8192; j >>= 1)
      k_sort_global<<<128, 256, 0, stream>>>(keys, k, j);
    k_sort_merge<<<8, 1024, 0, stream>>>(keys, k);
  }

  k_gather_sorted<<<24, 256, 0, stream>>>(keys, boxes, bx);
  k_nms_mask<<<6000, 128, 0, stream>>>(bx, mask);
  k_nms_scan<<<1, 64, 0, stream>>>(mask, sel);
  k_gather_prop<<<5, 64, 0, stream>>>(sel, bx, out_p, rois);

  k_roipool<<<300, 256, 0, stream>>>(fm, rois, pooled);

  k_gemm<<<dim3(32, 8), 512, 0, stream>>>(pooled, fc1_w, h1pre, 25088, 3136, 4096);
  k_bias_relu_bf<<<5120, 256, 0, stream>>>(h1pre, fc1_b, h1bf);
  k_gemm<<<dim3(32, 8), 512, 0, stream>>>(h1bf, fc2_w, h2pre, 4096, 512, 4096);
  k_bias_relu_bf<<<5120, 256, 0, stream>>>(h2pre, fc2_b, h2bf);
  k_head<<<300, 128, 0, stream>>>(h2bf, cw, cbias, rw, rbias, out_c, out_r);
}

// Round 2
// 1699.322 us; speedup vs baseline: 1.3459x; 1.3459x over previous
//
#include <hip/hip_runtime.h>
#include <stdint.h>

typedef float f32x4 __attribute__((ext_vector_type(4)));
typedef short s16x8 __attribute__((ext_vector_type(8)));
typedef unsigned long long u64;

__device__ __forceinline__ unsigned short f2bf(float f) {
  union { float f; unsigned u; } v; v.f = f;
  unsigned u = v.u;
  return (unsigned short)((u + 0x7FFFu + ((u >> 16) & 1u)) >> 16);
}
__device__ __forceinline__ float bf2f(unsigned short b) {
  union { unsigned u; float f; } v; v.u = ((unsigned)b) << 16; return v.f;
}

// ---------------- conv1: 3x3, 512->512, 64x64, SAME, +bias, relu --------------
// out y layout: [px=4096][oc=512] fp32
#define ICC 16
__global__ __launch_bounds__(256) void k_conv1(const float* __restrict__ fm,
                                               const float* __restrict__ w,
                                               const float* __restrict__ bias,
                                               float* __restrict__ y) {
  __shared__ float Ws[ICC * 9 * 68];
  __shared__ float Xs[ICC * 100];
  int bid = blockIdx.x;
  int ocg = bid & 7, sp = bid >> 3;
  int h0 = (sp >> 3) * 8, w0 = (sp & 7) * 8;
  int oc0 = ocg * 64;
  int t = threadIdx.x;
  int ocq = t >> 4, pxq = t & 15;
  int prow = pxq >> 1, pcolb = (pxq & 1) * 4;
  float acc[4][4] = {};
  for (int c0 = 0; c0 < 512; c0 += ICC) {
    for (int idx = t; idx < ICC * 100; idx += 256) {
      int ic = idx / 100; int rem = idx - ic * 100;
      int yy = rem / 10; int xx = rem - yy * 10;
      int gy = h0 + yy - 1, gx = w0 + xx - 1;
      float v = 0.f;
      if ((unsigned)gy < 64u && (unsigned)gx < 64u) v = fm[(c0 + ic) * 4096 + gy * 64 + gx];
      Xs[idx] = v;
    }
    for (int idx = t; idx < 64 * ICC * 9; idx += 256) {
      int oc = idx / (ICC * 9); int r = idx - oc * (ICC * 9);
      Ws[r * 68 + oc] = w[(oc0 + oc) * 4608 + c0 * 9 + r];
    }
    __syncthreads();
    for (int ic = 0; ic < ICC; ic++) {
      #pragma unroll
      for (int k = 0; k < 9; k++) {
        const int kh = k / 3, kw = k - kh * 3;
        f32x4 wv = *(const f32x4*)&Ws[(ic * 9 + k) * 68 + ocq * 4];
        const float* xp = &Xs[ic * 100 + (prow + kh) * 10 + pcolb + kw];
        float x0 = xp[0], x1 = xp[1], x2 = xp[2], x3 = xp[3];
        acc[0][0] += wv.x * x0; acc[0][1] += wv.x * x1; acc[0][2] += wv.x * x2; acc[0][3] += wv.x * x3;
        acc[1][0] += wv.y * x0; acc[1][1] += wv.y * x1; acc[1][2] += wv.y * x2; acc[1][3] += wv.y * x3;
        acc[2][0] += wv.z * x0; acc[2][1] += wv.z * x1; acc[2][2] += wv.z * x2; acc[2][3] += wv.z * x3;
        acc[3][0] += wv.w * x0; acc[3][1] += wv.w * x1; acc[3][2] += wv.w * x2; acc[3][3] += wv.w * x3;
      }
    }
    __syncthreads();
  }
  float b0 = bias[oc0 + ocq * 4 + 0], b1 = bias[oc0 + ocq * 4 + 1];
  float b2 = bias[oc0 + ocq * 4 + 2], b3 = bias[oc0 + ocq * 4 + 3];
  #pragma unroll
  for (int j = 0; j < 4; j++) {
    int px = (h0 + prow) * 64 + (w0 + pcolb + j);
    f32x4 v;
    v.x = fmaxf(acc[0][j] + b0, 0.f);
    v.y = fmaxf(acc[1][j] + b1, 0.f);
    v.z = fmaxf(acc[2][j] + b2, 0.f);
    v.w = fmaxf(acc[3][j] + b3, 0.f);
    *(f32x4*)&y[(u64)px * 512 + oc0 + ocq * 4] = v;
  }
}

// --------------- 1x1 convs: scores (sigmoid) + deltas ------------------------
__global__ __launch_bounds__(256) void k_rpn1x1(const float* __restrict__ y,
                                                const float* __restrict__ cw, const float* __restrict__ cb,
                                                const float* __restrict__ bw, const float* __restrict__ bb,
                                                float* __restrict__ out_s, float* __restrict__ out_d) {
  __shared__ float Ys[16 * 516];
  int px0 = blockIdx.x * 16;
  int t = threadIdx.x;
  for (int c = t; c < 16 * 128; c += 256) {
    int p = c >> 7, seg = c & 127;
    f32x4 v = *(const f32x4*)&y[(u64)(px0 + p) * 512 + seg * 4];
    *(f32x4*)&Ys[p * 516 + seg * 4] = v;
  }
  __syncthreads();
  int px = t & 15, og = t >> 4;
  const float* yr = &Ys[px * 516];
  for (int n = og; n < 45; n += 16) {
    const float* wr = (n < 9) ? &cw[n * 512] : &bw[(n - 9) * 512];
    float acc = 0.f;
    for (int k = 0; k < 512; k += 4) {
      f32x4 wv = *(const f32x4*)&wr[k];
      acc += wv.x * yr[k] + wv.y * yr[k + 1] + wv.z * yr[k + 2] + wv.w * yr[k + 3];
    }
    int gpx = px0 + px;
    if (n < 9) {
      float s = acc + cb[n];
      out_s[gpx * 9 + n] = 1.f / (1.f + expf(-s));
    } else {
      out_d[gpx * 36 + (n - 9)] = acc + bb[n - 9];
    }
  }
}

// --------------- box decode + sort keys --------------------------------------
__global__ void k_decode(const float* __restrict__ sc, const float* __restrict__ dl,
                         const float* __restrict__ amap,
                         float* __restrict__ boxes, u64* __restrict__ keys) {
  int i = blockIdx.x * 256 + threadIdx.x;
  if (i >= 65536) return;
  if (i < 36864) {
    int px = i / 9, a = i - px * 9;
    const float* A = &amap[i * 4];
    const float* D = &dl[px * 36 + a * 4];
    float cy = A[0] + D[0] * A[2];
    float cx = A[1] + D[1] * A[3];
    float hh = A[2] * expf(D[2]);
    float ww = A[3] * expf(D[3]);
    float y1 = fminf(fmaxf(cy - 0.5f * hh, 0.f), 1023.f);
    float x1 = fminf(fmaxf(cx - 0.5f * ww, 0.f), 1023.f);
    float y2 = fminf(fmaxf(cy + 0.5f * hh, 0.f), 1023.f);
    float x2 = fminf(fmaxf(cx + 0.5f * ww, 0.f), 1023.f);
    f32x4 v; v.x = y1; v.y = x1; v.z = y2; v.w = x2;
    *(f32x4*)&boxes[i * 4] = v;
    unsigned bits = __float_as_uint(sc[i]);
    u64 key = ((u64)bits << 16) | (u64)(0xFFFFu - (unsigned)i);
    keys[i] = ~key;  // ascending sort of ~key == descending by (score, -idx)
  } else {
    keys[i] = ~0ull;
  }
}

// --------------- bitonic sort of 65536 u64 keys (ascending) ------------------
__global__ __launch_bounds__(1024) void k_sort_local(u64* __restrict__ keys) {
  __shared__ u64 S[8192];
  int base = blockIdx.x * 8192;
  for (int i = threadIdx.x; i < 8192; i += 1024) S[i] = keys[base + i];
  __syncthreads();
  for (int k = 2; k <= 8192; k <<= 1) {
    for (int j = k >> 1; j > 0; j >>= 1) {
      for (int p = threadIdx.x; p < 4096; p += 1024) {
        int i = ((p & ~(j - 1)) << 1) | (p & (j - 1));
        int ix = i | j;
        bool up = (((base + i) & k) == 0);
        u64 a = S[i], c = S[ix];
        if ((a > c) == up) { S[i] = c; S[ix] = a; }
      }
      __syncthreads();
    }
  }
  for (int i = threadIdx.x; i < 8192; i += 1024) keys[base + i] = S[i];
}

__global__ void k_sort_global(u64* __restrict__ keys, int k, int j) {
  int p = blockIdx.x * 256 + threadIdx.x;
  int i = ((p & ~(j - 1)) << 1) | (p & (j - 1));
  int ix = i | j;
  bool up = ((i & k) == 0);
  u64 a = keys[i], c = keys[ix];
  if ((a > c) == up) { keys[i] = c; keys[ix] = a; }
}

__global__ __launch_bounds__(1024) void k_sort_merge(u64* __restrict__ keys, int k) {
  __shared__ u64 S[8192];
  int base = blockIdx.x * 8192;
  for (int i = threadIdx.x; i < 8192; i += 1024) S[i] = keys[base + i];
  __syncthreads();
  for (int j = 4096; j > 0; j >>= 1) {
    for (int p = threadIdx.x; p < 4096; p += 1024) {
      int i = ((p & ~(j - 1)) << 1) | (p & (j - 1));
      int ix = i | j;
      bool up = (((base + i) & k) == 0);
      u64 a = S[i], c = S[ix];
      if ((a > c) == up) { S[i] = c; S[ix] = a; }
    }
    __syncthreads();
  }
  for (int i = threadIdx.x; i < 8192; i += 1024) keys[base + i] = S[i];
}

__global__ void k_gather_sorted(const u64* __restrict__ keys, const float* __restrict__ boxes,
                                float* __restrict__ bx) {
  int p = blockIdx.x * 256 + threadIdx.x;
  if (p >= 6000) return;
  u64 key = ~keys[p];
  int idx = 0xFFFF - (int)(key & 0xFFFFull);
  *(f32x4*)&bx[p * 4] = *(const f32x4*)&boxes[idx * 4];
}

// --------------- NMS: suppression bitmask + sequential scan ------------------
__global__ __launch_bounds__(128) void k_nms_mask(const float* __restrict__ bx, u64* __restrict__ mask) {
  int i = blockIdx.x;
  int w = threadIdx.x;
  if (w >= 94) return;
  f32x4 bi = *(const f32x4*)&bx[i * 4];
  float ai = (bi.z - bi.x) * (bi.w - bi.y);
  u64 m = 0;
  int j0 = w * 64;
  for (int b = 0; b < 64; b++) {
    int j = j0 + b;
    if (j >= 6000) break;
    if (j <= i) continue;
    f32x4 bj = *(const f32x4*)&bx[j * 4];
    float yy1 = fmaxf(bi.x, bj.x), xx1 = fmaxf(bi.y, bj.y);
    float yy2 = fminf(bi.z, bj.z), xx2 = fminf(bi.w, bj.w);
    float inter = fmaxf(yy2 - yy1, 0.f) * fmaxf(xx2 - xx1, 0.f);
    float aj = (bj.z - bj.x) * (bj.w - bj.y);
    float iou = inter / (ai + aj - inter + 1e-8f);
    if (iou > 0.7f) m |= (1ull << b);
  }
  mask[i * 94 + w] = m;
}

// Sequential greedy scan with EARLY EXIT: since bx is sorted descending by
// score, top_k(kept_scores, 300) == first 300 unsuppressed rows in index
// order. Suppression of row i depends only on unsuppressed j < i, so we can
// stop as soon as 300 keepers are found. Double-buffered chunk prefetch
// hides L2/L3 latency behind the per-row shfl/OR work.
__global__ __launch_bounds__(64) void k_nms_scan(const u64* __restrict__ mask, int* __restrict__ sel) {
  int lane = threadIdx.x;
  u64 rem0 = 0, rem1 = 0;
  int nkeep = 0;
  u64 cur0[16], cur1[16], nxt0[16], nxt1[16];
  bool l30 = (lane < 30);
  #pragma unroll
  for (int r = 0; r < 16; r++) {
    cur0[r] = mask[r * 94 + lane];
    cur1[r] = l30 ? mask[r * 94 + 64 + lane] : 0ull;
  }
  for (int c0 = 0; c0 < 6000; c0 += 16) {
    int n0 = c0 + 16;
    if (n0 < 6000) {
      #pragma unroll
      for (int r = 0; r < 16; r++) {
        nxt0[r] = mask[(n0 + r) * 94 + lane];
        nxt1[r] = l30 ? mask[(n0 + r) * 94 + 64 + lane] : 0ull;
      }
    }
    #pragma unroll
    for (int r = 0; r < 16; r++) {
      int i = c0 + r;
      int wi = i >> 6, bi = i & 63;
      u64 wv = (wi < 64) ? __shfl(rem0, wi, 64) : __shfl(rem1, wi - 64, 64);
      if (!((wv >> bi) & 1ull)) {
        if (lane == 0 && nkeep < 300) sel[nkeep] = i;
        nkeep++;
        rem0 |= cur0[r]; rem1 |= cur1[r];
      }
    }
    if (nkeep >= 300) return;
    #pragma unroll
    for (int r = 0; r < 16; r++) { cur0[r] = nxt0[r]; cur1[r] = nxt1[r]; }
  }
  // Fallback (<300 survivors after full scan): append suppressed rows in
  // index order — matches top_k's tie-break among the -inf entries.
  __shared__ u64 remS[94];
  remS[lane] = rem0;
  if (l30) remS[64 + lane] = rem1;
  __syncthreads();
  if (lane == 0) {
    int k = nkeep;
    for (int i = 0; i < 6000 && k < 300; i++) {
      if ((remS[i >> 6] >> (i & 63)) & 1ull) sel[k++] = i;
    }
  }
}

__global__ void k_gather_prop(const int* __restrict__ sel, const float* __restrict__ bx,
                              float* __restrict__ out_p, float* __restrict__ rois) {
  int r = blockIdx.x * 64 + threadIdx.x;
  if (r >= 300) return;
  int p = sel[r];
  float y1 = bx[p * 4 + 0], x1 = bx[p * 4 + 1], y2 = bx[p * 4 + 2], x2 = bx[p * 4 + 3];
  out_p[r * 4 + 0] = y1; out_p[r * 4 + 1] = x1; out_p[r * 4 + 2] = y2; out_p[r * 4 + 3] = x2;
  rois[r * 4 + 0] = x1; rois[r * 4 + 1] = y1; rois[r * 4 + 2] = x2; rois[r * 4 + 3] = y2;
}

// --------------- ROI max-pool 7x7 (exact ref semantics), out bf16 ------------
__global__ __launch_bounds__(256) void k_roipool(const float* __restrict__ fm,
                                                 const float* __restrict__ rois,
                                                 unsigned short* __restrict__ pooled) {
  int roi = blockIdx.x;
  __shared__ int hs[7], he[7], wls[7], wle[7];
  if (threadIdx.x < 28) {
    int kind = threadIdx.x / 7, p = threadIdx.x - kind * 7;
    float x1 = rintf(rois[roi * 4 + 0] * 0.0625f);
    float y1 = rintf(rois[roi * 4 + 1] * 0.0625f);
    float x2 = rintf(rois[roi * 4 + 2] * 0.0625f);
    float y2 = rintf(rois[roi * 4 + 3] * 0.0625f);
    float rw = fmaxf(x2 - x1 + 1.f, 1.f), rh = fmaxf(y2 - y1 + 1.f, 1.f);
    float bh = rh / 7.f, bw = rw / 7.f;
    float fp = (float)p;
    if (kind == 0) hs[p]  = (int)fminf(fmaxf(floorf(fp * bh) + y1, 0.f), 64.f);
    if (kind == 1) he[p]  = (int)fminf(fmaxf(ceilf((fp + 1.f) * bh) + y1, 0.f), 64.f);
    if (kind == 2) wls[p] = (int)fminf(fmaxf(floorf(fp * bw) + x1, 0.f), 64.f);
    if (kind == 3) wle[p] = (int)fminf(fmaxf(ceilf((fp + 1.f) * bw) + x1, 0.f), 64.f);
  }
  __syncthreads();
  for (int o = threadIdx.x; o < 512 * 49; o += 256) {
    int c = o / 49; int cell = o - c * 49;
    int ph = cell / 7, pw = cell - ph * 7;
    int y0 = hs[ph], y1e = he[ph], x0 = wls[pw], x1e = wle[pw];
    bool any = (y1e > y0) && (x1e > x0);
    float m = -1e30f;
    const float* base = &fm[c * 4096];
    for (int yy = y0; yy < y1e; yy++)
      for (int xx = x0; xx < x1e; xx++)
        m = fmaxf(m, base[yy * 64 + xx]);
    pooled[(u64)roi * 25088 + o] = f2bf(any ? m : 0.f);
  }
}

// --------------- big GEMM: C[320][N] += A_bf16[320][K] * B_f32[N][K]^T --------
// grid (N/128, S); K-split via atomicAdd into pre-zeroed Cpre.
__global__ __launch_bounds__(512) void k_gemm(const unsigned short* __restrict__ A,
                                              const float* __restrict__ B,
                                              float* __restrict__ Cpre,
                                              int K, int Kslice, int N) {
  __shared__ unsigned short As[320 * 40];
  int n0 = blockIdx.x * 128;
  int s = blockIdx.y;
  int t = threadIdx.x;
  int wave = t >> 6, lane = t & 63;
  int mg = wave & 1, ng = wave >> 1;
  int m0 = mg * 160;
  int n0w = n0 + ng * 32;
  int lr = lane & 15, lk = lane >> 4;
  f32x4 acc[10][2];
  #pragma unroll
  for (int mt = 0; mt < 10; mt++)
    for (int nt = 0; nt < 2; nt++) { acc[mt][nt].x = 0; acc[mt][nt].y = 0; acc[mt][nt].z = 0; acc[mt][nt].w = 0; }
  int kbeg = s * Kslice, kend = kbeg + Kslice;
  for (int k0 = kbeg; k0 < kend; k0 += 32) {
    for (int c = t; c < 1280; c += 512) {
      int m = c >> 2, seg = (c & 3) * 8;
      *(uint4*)&As[m * 40 + seg] = *(const uint4*)&A[(u64)m * K + k0 + seg];
    }
    __syncthreads();
    s16x8 bfrag[2];
    #pragma unroll
    for (int nt = 0; nt < 2; nt++) {
      const float* bp = &B[(u64)(n0w + nt * 16 + lr) * K + k0 + lk * 8];
      f32x4 b0 = *(const f32x4*)bp;
      f32x4 b1 = *(const f32x4*)(bp + 4);
      s16x8 f;
      f[0] = (short)f2bf(b0.x); f[1] = (short)f2bf(b0.y); f[2] = (short)f2bf(b0.z); f[3] = (short)f2bf(b0.w);
      f[4] = (short)f2bf(b1.x); f[5] = (short)f2bf(b1.y); f[6] = (short)f2bf(b1.z); f[7] = (short)f2bf(b1.w);
      bfrag[nt] = f;
    }
    #pragma unroll
    for (int mt = 0; mt < 10; mt++) {
      s16x8 afrag = *(const s16x8*)&As[(m0 + mt * 16 + lr) * 40 + lk * 8];
      acc[mt][0] = __builtin_amdgcn_mfma_f32_16x16x32_bf16(afrag, bfrag[0], acc[mt][0], 0, 0, 0);
      acc[mt][1] = __builtin_amdgcn_mfma_f32_16x16x32_bf16(afrag, bfrag[1], acc[mt][1], 0, 0, 0);
    }
    __syncthreads();
  }
  #pragma unroll
  for (int mt = 0; mt < 10; mt++)
    for (int nt = 0; nt < 2; nt++)
      for (int r = 0; r < 4; r++) {
        int m = m0 + mt * 16 + lk * 4 + r;
        int n = n0w + nt * 16 + lr;
        atomicAdd(&Cpre[(u64)m * N + n], acc[mt][nt][r]);
      }
}

__global__ void k_bias_relu_bf(const float* __restrict__ pre, const float* __restrict__ bias,
                               unsigned short* __restrict__ outb) {
  int i = blockIdx.x * 256 + threadIdx.x;  // 320*4096 total
  float v = pre[i] + bias[i & 4095];
  outb[i] = f2bf(fmaxf(v, 0.f));
}

// --------------- heads: cls softmax + reg ------------------------------------
__global__ __launch_bounds__(128) void k_head(const unsigned short* __restrict__ h2,
                                              const float* __restrict__ cw, const float* __restrict__ cb,
                                              const float* __restrict__ rw, const float* __restrict__ rb,
                                              float* __restrict__ out_cls, float* __restrict__ out_reg) {
  __shared__ float Hs[4096];
  __shared__ float logits[101];
  __shared__ float es[21];
  int r = blockIdx.x, t = threadIdx.x;
  for (int c = t; c < 512; c += 128) {
    uint4 raw = *(const uint4*)&h2[(u64)r * 4096 + c * 8];
    unsigned short* sp = (unsigned short*)&raw;
    #pragma unroll
    for (int q = 0; q < 8; q++) Hs[c * 8 + q] = bf2f(sp[q]);
  }
  __syncthreads();
  for (int n = t; n < 101; n += 128) {
    const float* wrow = (n < 21) ? &cw[n * 4096] : &rw[(n - 21) * 4096];
    float acc = 0.f;
    for (int k = 0; k < 4096; k += 4) {
      f32x4 wv = *(const f32x4*)&wrow[k];
      acc += wv.x * Hs[k] + wv.y * Hs[k + 1] + wv.z * Hs[k + 2] + wv.w * Hs[k + 3];
    }
    acc += (n < 21) ? cb[n] : rb[n - 21];
    logits[n] = acc;
  }
  __syncthreads();
  if (t < 21) {
    float mx = logits[0];
    for (int q = 1; q < 21; q++) mx = fmaxf(mx, logits[q]);
    es[t] = expf(logits[t] - mx);
  }
  __syncthreads();
  if (t < 21) {
    float sum = 0.f;
    for (int q = 0; q < 21; q++) sum += es[q];
    out_cls[r * 21 + t] = es[t] / sum;
  }
  if (t >= 21 && t < 101) out_reg[r * 80 + (t - 21)] = logits[t];
}

// ------------------------------- launcher ------------------------------------
extern "C" void kernel_launch(void* const* d_in, const int* in_sizes, int n_in,
                              void* d_out, int out_size, void* d_ws, size_t ws_size,
                              hipStream_t stream) {
  (void)in_sizes; (void)n_in; (void)out_size; (void)ws_size;
  const float* fm     = (const float*)d_in[0];
  const float* amap   = (const float*)d_in[1];
  const float* conv_w = (const float*)d_in[3];
  const float* conv_b = (const float*)d_in[4];
  const float* cls_w  = (const float*)d_in[5];
  const float* cls_b  = (const float*)d_in[6];
  const float* box_w  = (const float*)d_in[7];
  const float* box_b  = (const float*)d_in[8];
  const float* fc1_w  = (const float*)d_in[9];
  const float* fc1_b  = (const float*)d_in[10];
  const float* fc2_w  = (const float*)d_in[11];
  const float* fc2_b  = (const float*)d_in[12];
  const float* cw     = (const float*)d_in[13];
  const float* cbias  = (const float*)d_in[14];
  const float* rw     = (const float*)d_in[15];
  const float* rbias  = (const float*)d_in[16];

  float* out_s = (float*)d_out;           // 36864
  float* out_d = out_s + 36864;           // 147456
  float* out_p = out_d + 147456;          // 1200
  float* out_c = out_p + 1200;            // 6300
  float* out_r = out_c + 6300;            // 24000

  char* ws = (char*)d_ws;
  // phase-1 overlay region [0, ~15.05MB) is later reused by `pooled` (rows 300+ pad
  // live at [15,052,800, 16,056,320) and are untouched by phase 1).
  unsigned short* pooled = (unsigned short*)(ws + 0);          // 320*25088*2 = 16,056,320
  u64*   mask  = (u64*)  (ws + 0);                             // 6000*94*8 = 4,512,000
  float* y     = (float*)(ws + 4718592);                       // 4096*512*4 = 8,388,608
  float* boxes = (float*)(ws + 13107200);                      // 36864*4*4 = 589,824
  u64*   keys  = (u64*)  (ws + 13697024);                      // 65536*8 = 524,288 (ends 14,221,312)
  float* bx    = (float*)(ws + 16056320);                      // 6000*4*4 = 96,000
  int*   sel   = (int*)  (ws + 16152320);                      // 300*4 (pad 1280)
  float* rois  = (float*)(ws + 16153600);                      // 300*4*4 = 4,800
  float* h1pre = (float*)(ws + 16158400);                      // 320*4096*4 = 5,242,880
  unsigned short* h1bf = (unsigned short*)(ws + 21401280);     // 320*4096*2 = 2,621,440
  float* h2pre = (float*)(ws + 24022720);                      // 5,242,880
  unsigned short* h2bf = (unsigned short*)(ws + 29265600);     // 2,621,440  (end ~31.9MB)

  hipMemsetAsync(h1pre, 0, (size_t)320 * 4096 * 4, stream);
  hipMemsetAsync(h2pre, 0, (size_t)320 * 4096 * 4, stream);
  hipMemsetAsync((char*)pooled + (size_t)300 * 25088 * 2, 0, (size_t)20 * 25088 * 2, stream);

  k_conv1<<<512, 256, 0, stream>>>(fm, conv_w, conv_b, y);
  k_rpn1x1<<<256, 256, 0, stream>>>(y, cls_w, cls_b, box_w, box_b, out_s, out_d);
  k_decode<<<256, 256, 0, stream>>>(out_s, out_d, amap, boxes, keys);

  k_sort_local<<<8, 1024, 0, stream>>>(keys);
  for (int k = 16384; k <= 65536; k <<= 1) {
    for (int j = k >> 1; j >= 8192; j >>= 1)
      k_sort_global<<<128, 256, 0, stream>>>(keys, k, j);
    k_sort_merge<<<8, 1024, 0, stream>>>(keys, k);
  }

  k_gather_sorted<<<24, 256, 0, stream>>>(keys, boxes, bx);
  k_nms_mask<<<6000, 128, 0, stream>>>(bx, mask);
  k_nms_scan<<<1, 64, 0, stream>>>(mask, sel);
  k_gather_prop<<<5, 64, 0, stream>>>(sel, bx, out_p, rois);

  k_roipool<<<300, 256, 0, stream>>>(fm, rois, pooled);

  k_gemm<<<dim3(32, 8), 512, 0, stream>>>(pooled, fc1_w, h1pre, 25088, 3136, 4096);
  k_bias_relu_bf<<<5120, 256, 0, stream>>>(h1pre, fc1_b, h1bf);
  k_gemm<<<dim3(32, 8), 512, 0, stream>>>(h1bf, fc2_w, h2pre, 4096, 512, 4096);
  k_bias_relu_bf<<<5120, 256, 0, stream>>>(h2pre, fc2_b, h2bf);
  k_head<<<300, 128, 0, stream>>>(h2bf, cw, cbias, rw, rbias, out_c, out_r);
}

// Round 3
// 1262.077 us; speedup vs baseline: 1.8123x; 1.3464x over previous
//
#include <hip/hip_runtime.h>
#include <stdint.h>

typedef float f32x4 __attribute__((ext_vector_type(4)));
typedef short s16x8 __attribute__((ext_vector_type(8)));
typedef unsigned long long u64;

__device__ __forceinline__ unsigned short f2bf(float f) {
  union { float f; unsigned u; } v; v.f = f;
  unsigned u = v.u;
  return (unsigned short)((u + 0x7FFFu + ((u >> 16) & 1u)) >> 16);
}
__device__ __forceinline__ float bf2f(unsigned short b) {
  union { unsigned u; float f; } v; v.u = ((unsigned)b) << 16; return v.f;
}

// ---------------- conv1: 3x3, 512->512, 64x64, SAME, +bias, relu --------------
// out y layout: [px=4096][oc=512] fp32
#define ICC 16
__global__ __launch_bounds__(256) void k_conv1(const float* __restrict__ fm,
                                               const float* __restrict__ w,
                                               const float* __restrict__ bias,
                                               float* __restrict__ y) {
  __shared__ float Ws[ICC * 9 * 68];
  __shared__ float Xs[ICC * 100];
  int bid = blockIdx.x;
  int ocg = bid & 7, sp = bid >> 3;
  int h0 = (sp >> 3) * 8, w0 = (sp & 7) * 8;
  int oc0 = ocg * 64;
  int t = threadIdx.x;
  int ocq = t >> 4, pxq = t & 15;
  int prow = pxq >> 1, pcolb = (pxq & 1) * 4;
  float acc[4][4] = {};
  for (int c0 = 0; c0 < 512; c0 += ICC) {
    for (int idx = t; idx < ICC * 100; idx += 256) {
      int ic = idx / 100; int rem = idx - ic * 100;
      int yy = rem / 10; int xx = rem - yy * 10;
      int gy = h0 + yy - 1, gx = w0 + xx - 1;
      float v = 0.f;
      if ((unsigned)gy < 64u && (unsigned)gx < 64u) v = fm[(c0 + ic) * 4096 + gy * 64 + gx];
      Xs[idx] = v;
    }
    for (int idx = t; idx < 64 * ICC * 9; idx += 256) {
      int oc = idx / (ICC * 9); int r = idx - oc * (ICC * 9);
      Ws[r * 68 + oc] = w[(oc0 + oc) * 4608 + c0 * 9 + r];
    }
    __syncthreads();
    for (int ic = 0; ic < ICC; ic++) {
      #pragma unroll
      for (int k = 0; k < 9; k++) {
        const int kh = k / 3, kw = k - kh * 3;
        f32x4 wv = *(const f32x4*)&Ws[(ic * 9 + k) * 68 + ocq * 4];
        const float* xp = &Xs[ic * 100 + (prow + kh) * 10 + pcolb + kw];
        float x0 = xp[0], x1 = xp[1], x2 = xp[2], x3 = xp[3];
        acc[0][0] += wv.x * x0; acc[0][1] += wv.x * x1; acc[0][2] += wv.x * x2; acc[0][3] += wv.x * x3;
        acc[1][0] += wv.y * x0; acc[1][1] += wv.y * x1; acc[1][2] += wv.y * x2; acc[1][3] += wv.y * x3;
        acc[2][0] += wv.z * x0; acc[2][1] += wv.z * x1; acc[2][2] += wv.z * x2; acc[2][3] += wv.z * x3;
        acc[3][0] += wv.w * x0; acc[3][1] += wv.w * x1; acc[3][2] += wv.w * x2; acc[3][3] += wv.w * x3;
      }
    }
    __syncthreads();
  }
  float b0 = bias[oc0 + ocq * 4 + 0], b1 = bias[oc0 + ocq * 4 + 1];
  float b2 = bias[oc0 + ocq * 4 + 2], b3 = bias[oc0 + ocq * 4 + 3];
  #pragma unroll
  for (int j = 0; j < 4; j++) {
    int px = (h0 + prow) * 64 + (w0 + pcolb + j);
    f32x4 v;
    v.x = fmaxf(acc[0][j] + b0, 0.f);
    v.y = fmaxf(acc[1][j] + b1, 0.f);
    v.z = fmaxf(acc[2][j] + b2, 0.f);
    v.w = fmaxf(acc[3][j] + b3, 0.f);
    *(f32x4*)&y[(u64)px * 512 + oc0 + ocq * 4] = v;
  }
}

// --------------- 1x1 convs: scores (sigmoid) + deltas ------------------------
__global__ __launch_bounds__(256) void k_rpn1x1(const float* __restrict__ y,
                                                const float* __restrict__ cw, const float* __restrict__ cb,
                                                const float* __restrict__ bw, const float* __restrict__ bb,
                                                float* __restrict__ out_s, float* __restrict__ out_d) {
  __shared__ float Ys[16 * 516];
  int px0 = blockIdx.x * 16;
  int t = threadIdx.x;
  for (int c = t; c < 16 * 128; c += 256) {
    int p = c >> 7, seg = c & 127;
    f32x4 v = *(const f32x4*)&y[(u64)(px0 + p) * 512 + seg * 4];
    *(f32x4*)&Ys[p * 516 + seg * 4] = v;
  }
  __syncthreads();
  int px = t & 15, og = t >> 4;
  const float* yr = &Ys[px * 516];
  for (int n = og; n < 45; n += 16) {
    const float* wr = (n < 9) ? &cw[n * 512] : &bw[(n - 9) * 512];
    float acc = 0.f;
    for (int k = 0; k < 512; k += 4) {
      f32x4 wv = *(const f32x4*)&wr[k];
      acc += wv.x * yr[k] + wv.y * yr[k + 1] + wv.z * yr[k + 2] + wv.w * yr[k + 3];
    }
    int gpx = px0 + px;
    if (n < 9) {
      float s = acc + cb[n];
      out_s[gpx * 9 + n] = 1.f / (1.f + expf(-s));
    } else {
      out_d[gpx * 36 + (n - 9)] = acc + bb[n - 9];
    }
  }
}

// --------------- box decode + sort keys --------------------------------------
__global__ void k_decode(const float* __restrict__ sc, const float* __restrict__ dl,
                         const float* __restrict__ amap,
                         float* __restrict__ boxes, u64* __restrict__ keys) {
  int i = blockIdx.x * 256 + threadIdx.x;
  if (i >= 65536) return;
  if (i < 36864) {
    int px = i / 9, a = i - px * 9;
    const float* A = &amap[i * 4];
    const float* D = &dl[px * 36 + a * 4];
    float cy = A[0] + D[0] * A[2];
    float cx = A[1] + D[1] * A[3];
    float hh = A[2] * expf(D[2]);
    float ww = A[3] * expf(D[3]);
    float y1 = fminf(fmaxf(cy - 0.5f * hh, 0.f), 1023.f);
    float x1 = fminf(fmaxf(cx - 0.5f * ww, 0.f), 1023.f);
    float y2 = fminf(fmaxf(cy + 0.5f * hh, 0.f), 1023.f);
    float x2 = fminf(fmaxf(cx + 0.5f * ww, 0.f), 1023.f);
    f32x4 v; v.x = y1; v.y = x1; v.z = y2; v.w = x2;
    *(f32x4*)&boxes[i * 4] = v;
    unsigned bits = __float_as_uint(sc[i]);
    u64 key = ((u64)bits << 16) | (u64)(0xFFFFu - (unsigned)i);
    keys[i] = ~key;  // ascending sort of ~key == descending by (score, -idx)
  } else {
    keys[i] = ~0ull;
  }
}

// --------------- bitonic sort of 65536 u64 keys (ascending) ------------------
__global__ __launch_bounds__(1024) void k_sort_local(u64* __restrict__ keys) {
  __shared__ u64 S[8192];
  int base = blockIdx.x * 8192;
  for (int i = threadIdx.x; i < 8192; i += 1024) S[i] = keys[base + i];
  __syncthreads();
  for (int k = 2; k <= 8192; k <<= 1) {
    for (int j = k >> 1; j > 0; j >>= 1) {
      for (int p = threadIdx.x; p < 4096; p += 1024) {
        int i = ((p & ~(j - 1)) << 1) | (p & (j - 1));
        int ix = i | j;
        bool up = (((base + i) & k) == 0);
        u64 a = S[i], c = S[ix];
        if ((a > c) == up) { S[i] = c; S[ix] = a; }
      }
      __syncthreads();
    }
  }
  for (int i = threadIdx.x; i < 8192; i += 1024) keys[base + i] = S[i];
}

__global__ void k_sort_global(u64* __restrict__ keys, int k, int j) {
  int p = blockIdx.x * 256 + threadIdx.x;
  int i = ((p & ~(j - 1)) << 1) | (p & (j - 1));
  int ix = i | j;
  bool up = ((i & k) == 0);
  u64 a = keys[i], c = keys[ix];
  if ((a > c) == up) { keys[i] = c; keys[ix] = a; }
}

__global__ __launch_bounds__(1024) void k_sort_merge(u64* __restrict__ keys, int k) {
  __shared__ u64 S[8192];
  int base = blockIdx.x * 8192;
  for (int i = threadIdx.x; i < 8192; i += 1024) S[i] = keys[base + i];
  __syncthreads();
  for (int j = 4096; j > 0; j >>= 1) {
    for (int p = threadIdx.x; p < 4096; p += 1024) {
      int i = ((p & ~(j - 1)) << 1) | (p & (j - 1));
      int ix = i | j;
      bool up = (((base + i) & k) == 0);
      u64 a = S[i], c = S[ix];
      if ((a > c) == up) { S[i] = c; S[ix] = a; }
    }
    __syncthreads();
  }
  for (int i = threadIdx.x; i < 8192; i += 1024) keys[base + i] = S[i];
}

__global__ void k_gather_sorted(const u64* __restrict__ keys, const float* __restrict__ boxes,
                                float* __restrict__ bx) {
  int p = blockIdx.x * 256 + threadIdx.x;
  if (p >= 6000) return;
  u64 key = ~keys[p];
  int idx = 0xFFFF - (int)(key & 0xFFFFull);
  *(f32x4*)&bx[p * 4] = *(const f32x4*)&boxes[idx * 4];
}

// --------------- NMS: suppression bitmask + sequential scan ------------------
__global__ __launch_bounds__(128) void k_nms_mask(const float* __restrict__ bx, u64* __restrict__ mask) {
  int i = blockIdx.x;
  int w = threadIdx.x;
  if (w >= 94) return;
  f32x4 bi = *(const f32x4*)&bx[i * 4];
  float ai = (bi.z - bi.x) * (bi.w - bi.y);
  u64 m = 0;
  int j0 = w * 64;
  for (int b = 0; b < 64; b++) {
    int j = j0 + b;
    if (j >= 6000) break;
    if (j <= i) continue;
    f32x4 bj = *(const f32x4*)&bx[j * 4];
    float yy1 = fmaxf(bi.x, bj.x), xx1 = fmaxf(bi.y, bj.y);
    float yy2 = fminf(bi.z, bj.z), xx2 = fminf(bi.w, bj.w);
    float inter = fmaxf(yy2 - yy1, 0.f) * fmaxf(xx2 - xx1, 0.f);
    float aj = (bj.z - bj.x) * (bj.w - bj.y);
    float iou = inter / (ai + aj - inter + 1e-8f);
    if (iou > 0.7f) m |= (1ull << b);
  }
  mask[i * 94 + w] = m;
}

// Sequential greedy scan with EARLY EXIT: since bx is sorted descending by
// score, top_k(kept_scores, 300) == first 300 unsuppressed rows in index
// order. Suppression of row i depends only on unsuppressed j < i, so we can
// stop as soon as 300 keepers are found. Double-buffered chunk prefetch
// hides L2/L3 latency behind the per-row shfl/OR work.
__global__ __launch_bounds__(64) void k_nms_scan(const u64* __restrict__ mask, int* __restrict__ sel) {
  int lane = threadIdx.x;
  u64 rem0 = 0, rem1 = 0;
  int nkeep = 0;
  u64 cur0[16], cur1[16], nxt0[16], nxt1[16];
  bool l30 = (lane < 30);
  #pragma unroll
  for (int r = 0; r < 16; r++) {
    cur0[r] = mask[r * 94 + lane];
    cur1[r] = l30 ? mask[r * 94 + 64 + lane] : 0ull;
  }
  for (int c0 = 0; c0 < 6000; c0 += 16) {
    int n0 = c0 + 16;
    if (n0 < 6000) {
      #pragma unroll
      for (int r = 0; r < 16; r++) {
        nxt0[r] = mask[(n0 + r) * 94 + lane];
        nxt1[r] = l30 ? mask[(n0 + r) * 94 + 64 + lane] : 0ull;
      }
    }
    #pragma unroll
    for (int r = 0; r < 16; r++) {
      int i = c0 + r;
      int wi = i >> 6, bi = i & 63;
      u64 wv = (wi < 64) ? __shfl(rem0, wi, 64) : __shfl(rem1, wi - 64, 64);
      if (!((wv >> bi) & 1ull)) {
        if (lane == 0 && nkeep < 300) sel[nkeep] = i;
        nkeep++;
        rem0 |= cur0[r]; rem1 |= cur1[r];
      }
    }
    if (nkeep >= 300) return;
    #pragma unroll
    for (int r = 0; r < 16; r++) { cur0[r] = nxt0[r]; cur1[r] = nxt1[r]; }
  }
  // Fallback (<300 survivors after full scan): append suppressed rows in
  // index order — matches top_k's tie-break among the -inf entries.
  __shared__ u64 remS[94];
  remS[lane] = rem0;
  if (l30) remS[64 + lane] = rem1;
  __syncthreads();
  if (lane == 0) {
    int k = nkeep;
    for (int i = 0; i < 6000 && k < 300; i++) {
      if ((remS[i >> 6] >> (i & 63)) & 1ull) sel[k++] = i;
    }
  }
}

__global__ void k_gather_prop(const int* __restrict__ sel, const float* __restrict__ bx,
                              float* __restrict__ out_p, float* __restrict__ rois) {
  int r = blockIdx.x * 64 + threadIdx.x;
  if (r >= 300) return;
  int p = sel[r];
  float y1 = bx[p * 4 + 0], x1 = bx[p * 4 + 1], y2 = bx[p * 4 + 2], x2 = bx[p * 4 + 3];
  out_p[r * 4 + 0] = y1; out_p[r * 4 + 1] = x1; out_p[r * 4 + 2] = y2; out_p[r * 4 + 3] = x2;
  rois[r * 4 + 0] = x1; rois[r * 4 + 1] = y1; rois[r * 4 + 2] = x2; rois[r * 4 + 3] = y2;
}

// --------------- ROI max-pool 7x7 (exact ref semantics), out bf16 ------------
// One thread per output element: grid = 300 rois x 98 segs, 256 thr (98*256=25088).
__global__ __launch_bounds__(256) void k_roipool(const float* __restrict__ fm,
                                                 const float* __restrict__ rois,
                                                 unsigned short* __restrict__ pooled) {
  int roi = blockIdx.x / 98;
  int seg = blockIdx.x - roi * 98;
  __shared__ int hs[7], he[7], wls[7], wle[7];
  if (threadIdx.x < 28) {
    int kind = threadIdx.x / 7, p = threadIdx.x - kind * 7;
    float x1 = rintf(rois[roi * 4 + 0] * 0.0625f);
    float y1 = rintf(rois[roi * 4 + 1] * 0.0625f);
    float x2 = rintf(rois[roi * 4 + 2] * 0.0625f);
    float y2 = rintf(rois[roi * 4 + 3] * 0.0625f);
    float rw = fmaxf(x2 - x1 + 1.f, 1.f), rh = fmaxf(y2 - y1 + 1.f, 1.f);
    float bh = rh / 7.f, bw = rw / 7.f;
    float fp = (float)p;
    if (kind == 0) hs[p]  = (int)fminf(fmaxf(floorf(fp * bh) + y1, 0.f), 64.f);
    if (kind == 1) he[p]  = (int)fminf(fmaxf(ceilf((fp + 1.f) * bh) + y1, 0.f), 64.f);
    if (kind == 2) wls[p] = (int)fminf(fmaxf(floorf(fp * bw) + x1, 0.f), 64.f);
    if (kind == 3) wle[p] = (int)fminf(fmaxf(ceilf((fp + 1.f) * bw) + x1, 0.f), 64.f);
  }
  __syncthreads();
  int o = seg * 256 + threadIdx.x;  // < 25088
  int c = o / 49; int cell = o - c * 49;
  int ph = cell / 7, pw = cell - ph * 7;
  int y0 = hs[ph], y1e = he[ph], x0 = wls[pw], x1e = wle[pw];
  bool any = (y1e > y0) && (x1e > x0);
  float m = -1e30f;
  const float* base = &fm[c * 4096];
  for (int yy = y0; yy < y1e; yy++)
    for (int xx = x0; xx < x1e; xx++)
      m = fmaxf(m, base[yy * 64 + xx]);
  pooled[(u64)roi * 25088 + o] = f2bf(any ? m : 0.f);
}

// --------------- big GEMM: C[320][N] += A_bf16[320][K] * B_f32[N][K]^T --------
// grid (N/128, S); K-split via atomicAdd into pre-zeroed Cpre.
__global__ __launch_bounds__(512) void k_gemm(const unsigned short* __restrict__ A,
                                              const float* __restrict__ B,
                                              float* __restrict__ Cpre,
                                              int K, int Kslice, int N) {
  __shared__ unsigned short As[320 * 40];
  int n0 = blockIdx.x * 128;
  int s = blockIdx.y;
  int t = threadIdx.x;
  int wave = t >> 6, lane = t & 63;
  int mg = wave & 1, ng = wave >> 1;
  int m0 = mg * 160;
  int n0w = n0 + ng * 32;
  int lr = lane & 15, lk = lane >> 4;
  f32x4 acc[10][2];
  #pragma unroll
  for (int mt = 0; mt < 10; mt++)
    for (int nt = 0; nt < 2; nt++) { acc[mt][nt].x = 0; acc[mt][nt].y = 0; acc[mt][nt].z = 0; acc[mt][nt].w = 0; }
  int kbeg = s * Kslice, kend = kbeg + Kslice;
  for (int k0 = kbeg; k0 < kend; k0 += 32) {
    for (int c = t; c < 1280; c += 512) {
      int m = c >> 2, seg = (c & 3) * 8;
      *(uint4*)&As[m * 40 + seg] = *(const uint4*)&A[(u64)m * K + k0 + seg];
    }
    __syncthreads();
    s16x8 bfrag[2];
    #pragma unroll
    for (int nt = 0; nt < 2; nt++) {
      const float* bp = &B[(u64)(n0w + nt * 16 + lr) * K + k0 + lk * 8];
      f32x4 b0 = *(const f32x4*)bp;
      f32x4 b1 = *(const f32x4*)(bp + 4);
      s16x8 f;
      f[0] = (short)f2bf(b0.x); f[1] = (short)f2bf(b0.y); f[2] = (short)f2bf(b0.z); f[3] = (short)f2bf(b0.w);
      f[4] = (short)f2bf(b1.x); f[5] = (short)f2bf(b1.y); f[6] = (short)f2bf(b1.z); f[7] = (short)f2bf(b1.w);
      bfrag[nt] = f;
    }
    #pragma unroll
    for (int mt = 0; mt < 10; mt++) {
      s16x8 afrag = *(const s16x8*)&As[(m0 + mt * 16 + lr) * 40 + lk * 8];
      acc[mt][0] = __builtin_amdgcn_mfma_f32_16x16x32_bf16(afrag, bfrag[0], acc[mt][0], 0, 0, 0);
      acc[mt][1] = __builtin_amdgcn_mfma_f32_16x16x32_bf16(afrag, bfrag[1], acc[mt][1], 0, 0, 0);
    }
    __syncthreads();
  }
  #pragma unroll
  for (int mt = 0; mt < 10; mt++)
    for (int nt = 0; nt < 2; nt++)
      for (int r = 0; r < 4; r++) {
        int m = m0 + mt * 16 + lk * 4 + r;
        int n = n0w + nt * 16 + lr;
        atomicAdd(&Cpre[(u64)m * N + n], acc[mt][nt][r]);
      }
}

__global__ void k_bias_relu_bf(const float* __restrict__ pre, const float* __restrict__ bias,
                               unsigned short* __restrict__ outb) {
  int i = blockIdx.x * 256 + threadIdx.x;  // 320*4096 total
  float v = pre[i] + bias[i & 4095];
  outb[i] = f2bf(fmaxf(v, 0.f));
}

// --------------- heads: cls softmax + reg ------------------------------------
__global__ __launch_bounds__(128) void k_head(const unsigned short* __restrict__ h2,
                                              const float* __restrict__ cw, const float* __restrict__ cb,
                                              const float* __restrict__ rw, const float* __restrict__ rb,
                                              float* __restrict__ out_cls, float* __restrict__ out_reg) {
  __shared__ float Hs[4096];
  __shared__ float logits[101];
  __shared__ float es[21];
  int r = blockIdx.x, t = threadIdx.x;
  for (int c = t; c < 512; c += 128) {
    uint4 raw = *(const uint4*)&h2[(u64)r * 4096 + c * 8];
    unsigned short* sp = (unsigned short*)&raw;
    #pragma unroll
    for (int q = 0; q < 8; q++) Hs[c * 8 + q] = bf2f(sp[q]);
  }
  __syncthreads();
  for (int n = t; n < 101; n += 128) {
    const float* wrow = (n < 21) ? &cw[n * 4096] : &rw[(n - 21) * 4096];
    float acc = 0.f;
    for (int k = 0; k < 4096; k += 4) {
      f32x4 wv = *(const f32x4*)&wrow[k];
      acc += wv.x * Hs[k] + wv.y * Hs[k + 1] + wv.z * Hs[k + 2] + wv.w * Hs[k + 3];
    }
    acc += (n < 21) ? cb[n] : rb[n - 21];
    logits[n] = acc;
  }
  __syncthreads();
  if (t < 21) {
    float mx = logits[0];
    for (int q = 1; q < 21; q++) mx = fmaxf(mx, logits[q]);
    es[t] = expf(logits[t] - mx);
  }
  __syncthreads();
  if (t < 21) {
    float sum = 0.f;
    for (int q = 0; q < 21; q++) sum += es[q];
    out_cls[r * 21 + t] = es[t] / sum;
  }
  if (t >= 21 && t < 101) out_reg[r * 80 + (t - 21)] = logits[t];
}

// ------------------------------- launcher ------------------------------------
extern "C" void kernel_launch(void* const* d_in, const int* in_sizes, int n_in,
                              void* d_out, int out_size, void* d_ws, size_t ws_size,
                              hipStream_t stream) {
  (void)in_sizes; (void)n_in; (void)out_size; (void)ws_size;
  const float* fm     = (const float*)d_in[0];
  const float* amap   = (const float*)d_in[1];
  const float* conv_w = (const float*)d_in[3];
  const float* conv_b = (const float*)d_in[4];
  const float* cls_w  = (const float*)d_in[5];
  const float* cls_b  = (const float*)d_in[6];
  const float* box_w  = (const float*)d_in[7];
  const float* box_b  = (const float*)d_in[8];
  const float* fc1_w  = (const float*)d_in[9];
  const float* fc1_b  = (const float*)d_in[10];
  const float* fc2_w  = (const float*)d_in[11];
  const float* fc2_b  = (const float*)d_in[12];
  const float* cw     = (const float*)d_in[13];
  const float* cbias  = (const float*)d_in[14];
  const float* rw     = (const float*)d_in[15];
  const float* rbias  = (const float*)d_in[16];

  float* out_s = (float*)d_out;           // 36864
  float* out_d = out_s + 36864;           // 147456
  float* out_p = out_d + 147456;          // 1200
  float* out_c = out_p + 1200;            // 6300
  float* out_r = out_c + 6300;            // 24000

  char* ws = (char*)d_ws;
  // phase-1 overlay region [0, ~15.05MB) is later reused by `pooled` (rows 300+ pad
  // live at [15,052,800, 16,056,320) and are untouched by phase 1).
  unsigned short* pooled = (unsigned short*)(ws + 0);          // 320*25088*2 = 16,056,320
  u64*   mask  = (u64*)  (ws + 0);                             // 6000*94*8 = 4,512,000
  float* y     = (float*)(ws + 4718592);                       // 4096*512*4 = 8,388,608
  float* boxes = (float*)(ws + 13107200);                      // 36864*4*4 = 589,824
  u64*   keys  = (u64*)  (ws + 13697024);                      // 65536*8 = 524,288 (ends 14,221,312)
  float* bx    = (float*)(ws + 16056320);                      // 6000*4*4 = 96,000
  int*   sel   = (int*)  (ws + 16152320);                      // 300*4 (pad 1280)
  float* rois  = (float*)(ws + 16153600);                      // 300*4*4 = 4,800
  float* h1pre = (float*)(ws + 16158400);                      // 320*4096*4 = 5,242,880
  unsigned short* h1bf = (unsigned short*)(ws + 21401280);     // 320*4096*2 = 2,621,440
  float* h2pre = (float*)(ws + 24022720);                      // 5,242,880
  unsigned short* h2bf = (unsigned short*)(ws + 29265600);     // 2,621,440  (end ~31.9MB)

  hipMemsetAsync(h1pre, 0, (size_t)320 * 4096 * 4, stream);
  hipMemsetAsync(h2pre, 0, (size_t)320 * 4096 * 4, stream);
  hipMemsetAsync((char*)pooled + (size_t)300 * 25088 * 2, 0, (size_t)20 * 25088 * 2, stream);

  k_conv1<<<512, 256, 0, stream>>>(fm, conv_w, conv_b, y);
  k_rpn1x1<<<256, 256, 0, stream>>>(y, cls_w, cls_b, box_w, box_b, out_s, out_d);
  k_decode<<<256, 256, 0, stream>>>(out_s, out_d, amap, boxes, keys);

  k_sort_local<<<8, 1024, 0, stream>>>(keys);
  for (int k = 16384; k <= 65536; k <<= 1) {
    for (int j = k >> 1; j >= 8192; j >>= 1)
      k_sort_global<<<128, 256, 0, stream>>>(keys, k, j);
    k_sort_merge<<<8, 1024, 0, stream>>>(keys, k);
  }

  k_gather_sorted<<<24, 256, 0, stream>>>(keys, boxes, bx);
  k_nms_mask<<<6000, 128, 0, stream>>>(bx, mask);
  k_nms_scan<<<1, 64, 0, stream>>>(mask, sel);
  k_gather_prop<<<5, 64, 0, stream>>>(sel, bx, out_p, rois);

  k_roipool<<<300 * 98, 256, 0, stream>>>(fm, rois, pooled);

  k_gemm<<<dim3(32, 8), 512, 0, stream>>>(pooled, fc1_w, h1pre, 25088, 3136, 4096);
  k_bias_relu_bf<<<5120, 256, 0, stream>>>(h1pre, fc1_b, h1bf);
  k_gemm<<<dim3(32, 8), 512, 0, stream>>>(h1bf, fc2_w, h2pre, 4096, 512, 4096);
  k_bias_relu_bf<<<5120, 256, 0, stream>>>(h2pre, fc2_b, h2bf);
  k_head<<<300, 128, 0, stream>>>(h2bf, cw, cbias, rw, rbias, out_c, out_r);
}

// Round 4
// 1168.626 us; speedup vs baseline: 1.9572x; 1.0800x over previous
//
#include <hip/hip_runtime.h>
#include <stdint.h>

typedef float f32x4 __attribute__((ext_vector_type(4)));
typedef short s16x8 __attribute__((ext_vector_type(8)));
typedef unsigned long long u64;

__device__ __forceinline__ unsigned short f2bf(float f) {
  union { float f; unsigned u; } v; v.f = f;
  unsigned u = v.u;
  return (unsigned short)((u + 0x7FFFu + ((u >> 16) & 1u)) >> 16);
}
__device__ __forceinline__ float bf2f(unsigned short b) {
  union { unsigned u; float f; } v; v.u = ((unsigned)b) << 16; return v.f;
}

// ---------------- conv2: 3x3, 512->512, 64x64, SAME, K-split x4 --------------
// Block: 64 oc x (16h x 32w) px, one K-slice of 128 ic. Thread: 8 oc x 2r x 8c.
// Writes partial sums (no bias/relu) to ypart[s][px][oc]; epilogue in k_rpn1x1.
#define CONV_ICC 8
__global__ __launch_bounds__(256, 1) void k_conv2(const float* __restrict__ fm,
                                                  const float* __restrict__ w,
                                                  float* __restrict__ ypart) {
  __shared__ float Xs[CONV_ICC * 648];     // [ic][18 rows][pitch 36]
  __shared__ float Ws[CONV_ICC * 9 * 64];  // [ic][k][oc]
  int bid = blockIdx.x;
  int s = bid & 3, ocg = (bid >> 2) & 7, sp = bid >> 5;   // sp 0..7
  int h0 = (sp >> 1) * 16, w0 = (sp & 1) * 32;
  int oc0 = ocg * 64;
  int t = threadIdx.x;
  int g = t >> 5, p = t & 31;
  int pr = p >> 2, pc = (p & 3) * 8;
  int r0 = 2 * pr;
  float acc[2][8][8] = {};
  int cbase = s * 128;
  for (int chunk = 0; chunk < 16; chunk++) {
    int c0 = cbase + chunk * CONV_ICC;
    // stage X: 8 ic x 18 rows x 34 cols (halo +-1), pitch 36
    for (int idx = t; idx < CONV_ICC * 612; idx += 256) {
      int ic = idx / 612, rem = idx - ic * 612;
      int r = rem / 34, cc = rem - r * 34;
      int gy = h0 + r - 1, gx = w0 + cc - 1;
      float v = 0.f;
      if ((unsigned)gy < 64u && (unsigned)gx < 64u) v = fm[(c0 + ic) * 4096 + gy * 64 + gx];
      Xs[ic * 648 + r * 36 + cc] = v;
    }
    // stage W: [ic][k][oc]
    for (int idx = t; idx < CONV_ICC * 9 * 64; idx += 256) {
      int oc = idx & 63, rest = idx >> 6;
      int ic = rest / 9, k = rest - ic * 9;
      Ws[idx] = w[(u64)(oc0 + oc) * 4608 + (c0 + ic) * 9 + k];
    }
    __syncthreads();
    for (int ic = 0; ic < CONV_ICC; ic++) {
      const float* xb = &Xs[ic * 648 + pc];
      float xr[4][10];
      #pragma unroll
      for (int r = 0; r < 4; r++)
        #pragma unroll
        for (int j = 0; j < 10; j++)
          xr[r][j] = xb[(r0 + r) * 36 + j];
      #pragma unroll
      for (int kh = 0; kh < 3; kh++) {
        #pragma unroll
        for (int kw = 0; kw < 3; kw++) {
          const float* wp = &Ws[(ic * 9 + kh * 3 + kw) * 64 + g * 8];
          f32x4 wa = *(const f32x4*)wp;
          f32x4 wb = *(const f32x4*)(wp + 4);
          float wv[8] = {wa.x, wa.y, wa.z, wa.w, wb.x, wb.y, wb.z, wb.w};
          #pragma unroll
          for (int o = 0; o < 8; o++) {
            #pragma unroll
            for (int j = 0; j < 8; j++) {
              acc[0][o][j] += wv[o] * xr[kh][kw + j];
              acc[1][o][j] += wv[o] * xr[kh + 1][kw + j];
            }
          }
        }
      }
    }
    __syncthreads();
  }
  float* yp = ypart + (u64)s * 2097152;
  #pragma unroll
  for (int d = 0; d < 2; d++) {
    int row = h0 + r0 + d, colb = w0 + pc;
    #pragma unroll
    for (int j = 0; j < 8; j++) {
      int pxg = row * 64 + colb + j;
      f32x4 v0, v1;
      v0.x = acc[d][0][j]; v0.y = acc[d][1][j]; v0.z = acc[d][2][j]; v0.w = acc[d][3][j];
      v1.x = acc[d][4][j]; v1.y = acc[d][5][j]; v1.z = acc[d][6][j]; v1.w = acc[d][7][j];
      f32x4* dst = (f32x4*)&yp[(u64)pxg * 512 + oc0 + g * 8];
      dst[0] = v0; dst[1] = v1;
    }
  }
}

// --------------- 1x1 convs: sum partials + bias + relu, then dots ------------
__global__ __launch_bounds__(256) void k_rpn1x1(const float* __restrict__ ypart,
                                                const float* __restrict__ conv_b,
                                                const float* __restrict__ cw, const float* __restrict__ cb,
                                                const float* __restrict__ bw, const float* __restrict__ bb,
                                                float* __restrict__ out_s, float* __restrict__ out_d) {
  __shared__ float Ys[16 * 516];
  int px0 = blockIdx.x * 16;
  int t = threadIdx.x;
  for (int c = t; c < 16 * 128; c += 256) {
    int p = c >> 7, seg = c & 127;
    u64 off = (u64)(px0 + p) * 512 + seg * 4;
    f32x4 v0 = *(const f32x4*)&ypart[off];
    f32x4 v1 = *(const f32x4*)&ypart[2097152 + off];
    f32x4 v2 = *(const f32x4*)&ypart[2 * 2097152 + off];
    f32x4 v3 = *(const f32x4*)&ypart[3 * (u64)2097152 + off];
    f32x4 b = *(const f32x4*)&conv_b[seg * 4];
    f32x4 r;
    r.x = fmaxf(v0.x + v1.x + v2.x + v3.x + b.x, 0.f);
    r.y = fmaxf(v0.y + v1.y + v2.y + v3.y + b.y, 0.f);
    r.z = fmaxf(v0.z + v1.z + v2.z + v3.z + b.z, 0.f);
    r.w = fmaxf(v0.w + v1.w + v2.w + v3.w + b.w, 0.f);
    *(f32x4*)&Ys[p * 516 + seg * 4] = r;
  }
  __syncthreads();
  int px = t & 15, og = t >> 4;
  const float* yr = &Ys[px * 516];
  for (int n = og; n < 45; n += 16) {
    const float* wr = (n < 9) ? &cw[n * 512] : &bw[(n - 9) * 512];
    float acc = 0.f;
    for (int k = 0; k < 512; k += 4) {
      f32x4 wv = *(const f32x4*)&wr[k];
      acc += wv.x * yr[k] + wv.y * yr[k + 1] + wv.z * yr[k + 2] + wv.w * yr[k + 3];
    }
    int gpx = px0 + px;
    if (n < 9) {
      float s = acc + cb[n];
      out_s[gpx * 9 + n] = 1.f / (1.f + expf(-s));
    } else {
      out_d[gpx * 36 + (n - 9)] = acc + bb[n - 9];
    }
  }
}

// --------------- box decode + sort keys --------------------------------------
__global__ void k_decode(const float* __restrict__ sc, const float* __restrict__ dl,
                         const float* __restrict__ amap,
                         float* __restrict__ boxes, u64* __restrict__ keys) {
  int i = blockIdx.x * 256 + threadIdx.x;
  if (i >= 65536) return;
  if (i < 36864) {
    int px = i / 9, a = i - px * 9;
    const float* A = &amap[i * 4];
    const float* D = &dl[px * 36 + a * 4];
    float cy = A[0] + D[0] * A[2];
    float cx = A[1] + D[1] * A[3];
    float hh = A[2] * expf(D[2]);
    float ww = A[3] * expf(D[3]);
    float y1 = fminf(fmaxf(cy - 0.5f * hh, 0.f), 1023.f);
    float x1 = fminf(fmaxf(cx - 0.5f * ww, 0.f), 1023.f);
    float y2 = fminf(fmaxf(cy + 0.5f * hh, 0.f), 1023.f);
    float x2 = fminf(fmaxf(cx + 0.5f * ww, 0.f), 1023.f);
    f32x4 v; v.x = y1; v.y = x1; v.z = y2; v.w = x2;
    *(f32x4*)&boxes[i * 4] = v;
    unsigned bits = __float_as_uint(sc[i]);
    u64 key = ((u64)bits << 16) | (u64)(0xFFFFu - (unsigned)i);
    keys[i] = ~key;  // ascending sort of ~key == descending by (score, -idx)
  } else {
    keys[i] = ~0ull;
  }
}

// --------------- bitonic sort of 65536 u64 keys (ascending) ------------------
__global__ __launch_bounds__(1024) void k_sort_local(u64* __restrict__ keys) {
  __shared__ u64 S[8192];
  int base = blockIdx.x * 8192;
  for (int i = threadIdx.x; i < 8192; i += 1024) S[i] = keys[base + i];
  __syncthreads();
  for (int k = 2; k <= 8192; k <<= 1) {
    for (int j = k >> 1; j > 0; j >>= 1) {
      for (int p = threadIdx.x; p < 4096; p += 1024) {
        int i = ((p & ~(j - 1)) << 1) | (p & (j - 1));
        int ix = i | j;
        bool up = (((base + i) & k) == 0);
        u64 a = S[i], c = S[ix];
        if ((a > c) == up) { S[i] = c; S[ix] = a; }
      }
      __syncthreads();
    }
  }
  for (int i = threadIdx.x; i < 8192; i += 1024) keys[base + i] = S[i];
}

__global__ void k_sort_global(u64* __restrict__ keys, int k, int j) {
  int p = blockIdx.x * 256 + threadIdx.x;
  int i = ((p & ~(j - 1)) << 1) | (p & (j - 1));
  int ix = i | j;
  bool up = ((i & k) == 0);
  u64 a = keys[i], c = keys[ix];
  if ((a > c) == up) { keys[i] = c; keys[ix] = a; }
}

__global__ __launch_bounds__(1024) void k_sort_merge(u64* __restrict__ keys, int k) {
  __shared__ u64 S[8192];
  int base = blockIdx.x * 8192;
  for (int i = threadIdx.x; i < 8192; i += 1024) S[i] = keys[base + i];
  __syncthreads();
  for (int j = 4096; j > 0; j >>= 1) {
    for (int p = threadIdx.x; p < 4096; p += 1024) {
      int i = ((p & ~(j - 1)) << 1) | (p & (j - 1));
      int ix = i | j;
      bool up = (((base + i) & k) == 0);
      u64 a = S[i], c = S[ix];
      if ((a > c) == up) { S[i] = c; S[ix] = a; }
    }
    __syncthreads();
  }
  for (int i = threadIdx.x; i < 8192; i += 1024) keys[base + i] = S[i];
}

__global__ void k_gather_sorted(const u64* __restrict__ keys, const float* __restrict__ boxes,
                                float* __restrict__ bx) {
  int p = blockIdx.x * 256 + threadIdx.x;
  if (p >= 6000) return;
  u64 key = ~keys[p];
  int idx = 0xFFFF - (int)(key & 0xFFFFull);
  *(f32x4*)&bx[p * 4] = *(const f32x4*)&boxes[idx * 4];
}

// --------------- NMS: suppression bitmask + sequential scan ------------------
__global__ __launch_bounds__(128) void k_nms_mask(const float* __restrict__ bx, u64* __restrict__ mask) {
  int i = blockIdx.x;
  int w = threadIdx.x;
  if (w >= 94) return;
  f32x4 bi = *(const f32x4*)&bx[i * 4];
  float ai = (bi.z - bi.x) * (bi.w - bi.y);
  u64 m = 0;
  int j0 = w * 64;
  for (int b = 0; b < 64; b++) {
    int j = j0 + b;
    if (j >= 6000) break;
    if (j <= i) continue;
    f32x4 bj = *(const f32x4*)&bx[j * 4];
    float yy1 = fmaxf(bi.x, bj.x), xx1 = fmaxf(bi.y, bj.y);
    float yy2 = fminf(bi.z, bj.z), xx2 = fminf(bi.w, bj.w);
    float inter = fmaxf(yy2 - yy1, 0.f) * fmaxf(xx2 - xx1, 0.f);
    float aj = (bj.z - bj.x) * (bj.w - bj.y);
    float iou = inter / (ai + aj - inter + 1e-8f);
    if (iou > 0.7f) m |= (1ull << b);
  }
  mask[i * 94 + w] = m;
}

// Sequential greedy scan with EARLY EXIT (see R1 notes): stops once 300
// keepers are found; fallback fills from suppressed set in index order.
__global__ __launch_bounds__(64) void k_nms_scan(const u64* __restrict__ mask, int* __restrict__ sel) {
  int lane = threadIdx.x;
  u64 rem0 = 0, rem1 = 0;
  int nkeep = 0;
  u64 cur0[16], cur1[16], nxt0[16], nxt1[16];
  bool l30 = (lane < 30);
  #pragma unroll
  for (int r = 0; r < 16; r++) {
    cur0[r] = mask[r * 94 + lane];
    cur1[r] = l30 ? mask[r * 94 + 64 + lane] : 0ull;
  }
  for (int c0 = 0; c0 < 6000; c0 += 16) {
    int n0 = c0 + 16;
    if (n0 < 6000) {
      #pragma unroll
      for (int r = 0; r < 16; r++) {
        nxt0[r] = mask[(n0 + r) * 94 + lane];
        nxt1[r] = l30 ? mask[(n0 + r) * 94 + 64 + lane] : 0ull;
      }
    }
    #pragma unroll
    for (int r = 0; r < 16; r++) {
      int i = c0 + r;
      int wi = i >> 6, bi = i & 63;
      u64 wv = (wi < 64) ? __shfl(rem0, wi, 64) : __shfl(rem1, wi - 64, 64);
      if (!((wv >> bi) & 1ull)) {
        if (lane == 0 && nkeep < 300) sel[nkeep] = i;
        nkeep++;
        rem0 |= cur0[r]; rem1 |= cur1[r];
      }
    }
    if (nkeep >= 300) return;
    #pragma unroll
    for (int r = 0; r < 16; r++) { cur0[r] = nxt0[r]; cur1[r] = nxt1[r]; }
  }
  __shared__ u64 remS[94];
  remS[lane] = rem0;
  if (l30) remS[64 + lane] = rem1;
  __syncthreads();
  if (lane == 0) {
    int k = nkeep;
    for (int i = 0; i < 6000 && k < 300; i++) {
      if ((remS[i >> 6] >> (i & 63)) & 1ull) sel[k++] = i;
    }
  }
}

__global__ void k_gather_prop(const int* __restrict__ sel, const float* __restrict__ bx,
                              float* __restrict__ out_p, float* __restrict__ rois) {
  int r = blockIdx.x * 64 + threadIdx.x;
  if (r >= 300) return;
  int p = sel[r];
  float y1 = bx[p * 4 + 0], x1 = bx[p * 4 + 1], y2 = bx[p * 4 + 2], x2 = bx[p * 4 + 3];
  out_p[r * 4 + 0] = y1; out_p[r * 4 + 1] = x1; out_p[r * 4 + 2] = y2; out_p[r * 4 + 3] = x2;
  rois[r * 4 + 0] = x1; rois[r * 4 + 1] = y1; rois[r * 4 + 2] = x2; rois[r * 4 + 3] = y2;
}

// --------------- ROI max-pool 7x7 (exact ref semantics), out bf16 ------------
__global__ __launch_bounds__(256) void k_roipool(const float* __restrict__ fm,
                                                 const float* __restrict__ rois,
                                                 unsigned short* __restrict__ pooled) {
  int roi = blockIdx.x / 98;
  int seg = blockIdx.x - roi * 98;
  __shared__ int hs[7], he[7], wls[7], wle[7];
  if (threadIdx.x < 28) {
    int kind = threadIdx.x / 7, p = threadIdx.x - kind * 7;
    float x1 = rintf(rois[roi * 4 + 0] * 0.0625f);
    float y1 = rintf(rois[roi * 4 + 1] * 0.0625f);
    float x2 = rintf(rois[roi * 4 + 2] * 0.0625f);
    float y2 = rintf(rois[roi * 4 + 3] * 0.0625f);
    float rw = fmaxf(x2 - x1 + 1.f, 1.f), rh = fmaxf(y2 - y1 + 1.f, 1.f);
    float bh = rh / 7.f, bw = rw / 7.f;
    float fp = (float)p;
    if (kind == 0) hs[p]  = (int)fminf(fmaxf(floorf(fp * bh) + y1, 0.f), 64.f);
    if (kind == 1) he[p]  = (int)fminf(fmaxf(ceilf((fp + 1.f) * bh) + y1, 0.f), 64.f);
    if (kind == 2) wls[p] = (int)fminf(fmaxf(floorf(fp * bw) + x1, 0.f), 64.f);
    if (kind == 3) wle[p] = (int)fminf(fmaxf(ceilf((fp + 1.f) * bw) + x1, 0.f), 64.f);
  }
  __syncthreads();
  int o = seg * 256 + threadIdx.x;  // < 25088
  int c = o / 49; int cell = o - c * 49;
  int ph = cell / 7, pw = cell - ph * 7;
  int y0 = hs[ph], y1e = he[ph], x0 = wls[pw], x1e = wle[pw];
  bool any = (y1e > y0) && (x1e > x0);
  float m = -1e30f;
  const float* base = &fm[c * 4096];
  for (int yy = y0; yy < y1e; yy++)
    for (int xx = x0; xx < x1e; xx++)
      m = fmaxf(m, base[yy * 64 + xx]);
  pooled[(u64)roi * 25088 + o] = f2bf(any ? m : 0.f);
}

// --------------- big GEMM: C[320][N] += A_bf16[320][K] * B_f32[N][K]^T --------
__global__ __launch_bounds__(512) void k_gemm(const unsigned short* __restrict__ A,
                                              const float* __restrict__ B,
                                              float* __restrict__ Cpre,
                                              int K, int Kslice, int N) {
  __shared__ unsigned short As[320 * 40];
  int n0 = blockIdx.x * 128;
  int s = blockIdx.y;
  int t = threadIdx.x;
  int wave = t >> 6, lane = t & 63;
  int mg = wave & 1, ng = wave >> 1;
  int m0 = mg * 160;
  int n0w = n0 + ng * 32;
  int lr = lane & 15, lk = lane >> 4;
  f32x4 acc[10][2];
  #pragma unroll
  for (int mt = 0; mt < 10; mt++)
    for (int nt = 0; nt < 2; nt++) { acc[mt][nt].x = 0; acc[mt][nt].y = 0; acc[mt][nt].z = 0; acc[mt][nt].w = 0; }
  int kbeg = s * Kslice, kend = kbeg + Kslice;
  for (int k0 = kbeg; k0 < kend; k0 += 32) {
    for (int c = t; c < 1280; c += 512) {
      int m = c >> 2, seg = (c & 3) * 8;
      *(uint4*)&As[m * 40 + seg] = *(const uint4*)&A[(u64)m * K + k0 + seg];
    }
    __syncthreads();
    s16x8 bfrag[2];
    #pragma unroll
    for (int nt = 0; nt < 2; nt++) {
      const float* bp = &B[(u64)(n0w + nt * 16 + lr) * K + k0 + lk * 8];
      f32x4 b0 = *(const f32x4*)bp;
      f32x4 b1 = *(const f32x4*)(bp + 4);
      s16x8 f;
      f[0] = (short)f2bf(b0.x); f[1] = (short)f2bf(b0.y); f[2] = (short)f2bf(b0.z); f[3] = (short)f2bf(b0.w);
      f[4] = (short)f2bf(b1.x); f[5] = (short)f2bf(b1.y); f[6] = (short)f2bf(b1.z); f[7] = (short)f2bf(b1.w);
      bfrag[nt] = f;
    }
    #pragma unroll
    for (int mt = 0; mt < 10; mt++) {
      s16x8 afrag = *(const s16x8*)&As[(m0 + mt * 16 + lr) * 40 + lk * 8];
      acc[mt][0] = __builtin_amdgcn_mfma_f32_16x16x32_bf16(afrag, bfrag[0], acc[mt][0], 0, 0, 0);
      acc[mt][1] = __builtin_amdgcn_mfma_f32_16x16x32_bf16(afrag, bfrag[1], acc[mt][1], 0, 0, 0);
    }
    __syncthreads();
  }
  #pragma unroll
  for (int mt = 0; mt < 10; mt++)
    for (int nt = 0; nt < 2; nt++)
      for (int r = 0; r < 4; r++) {
        int m = m0 + mt * 16 + lk * 4 + r;
        int n = n0w + nt * 16 + lr;
        atomicAdd(&Cpre[(u64)m * N + n], acc[mt][nt][r]);
      }
}

__global__ void k_bias_relu_bf(const float* __restrict__ pre, const float* __restrict__ bias,
                               unsigned short* __restrict__ outb) {
  int i = blockIdx.x * 256 + threadIdx.x;  // 320*4096 total
  float v = pre[i] + bias[i & 4095];
  outb[i] = f2bf(fmaxf(v, 0.f));
}

// --------------- heads: cls softmax + reg ------------------------------------
__global__ __launch_bounds__(128) void k_head(const unsigned short* __restrict__ h2,
                                              const float* __restrict__ cw, const float* __restrict__ cb,
                                              const float* __restrict__ rw, const float* __restrict__ rb,
                                              float* __restrict__ out_cls, float* __restrict__ out_reg) {
  __shared__ float Hs[4096];
  __shared__ float logits[101];
  __shared__ float es[21];
  int r = blockIdx.x, t = threadIdx.x;
  for (int c = t; c < 512; c += 128) {
    uint4 raw = *(const uint4*)&h2[(u64)r * 4096 + c * 8];
    unsigned short* sp = (unsigned short*)&raw;
    #pragma unroll
    for (int q = 0; q < 8; q++) Hs[c * 8 + q] = bf2f(sp[q]);
  }
  __syncthreads();
  for (int n = t; n < 101; n += 128) {
    const float* wrow = (n < 21) ? &cw[n * 4096] : &rw[(n - 21) * 4096];
    float acc = 0.f;
    for (int k = 0; k < 4096; k += 4) {
      f32x4 wv = *(const f32x4*)&wrow[k];
      acc += wv.x * Hs[k] + wv.y * Hs[k + 1] + wv.z * Hs[k + 2] + wv.w * Hs[k + 3];
    }
    acc += (n < 21) ? cb[n] : rb[n - 21];
    logits[n] = acc;
  }
  __syncthreads();
  if (t < 21) {
    float mx = logits[0];
    for (int q = 1; q < 21; q++) mx = fmaxf(mx, logits[q]);
    es[t] = expf(logits[t] - mx);
  }
  __syncthreads();
  if (t < 21) {
    float sum = 0.f;
    for (int q = 0; q < 21; q++) sum += es[q];
    out_cls[r * 21 + t] = es[t] / sum;
  }
  if (t >= 21 && t < 101) out_reg[r * 80 + (t - 21)] = logits[t];
}

// ------------------------------- launcher ------------------------------------
extern "C" void kernel_launch(void* const* d_in, const int* in_sizes, int n_in,
                              void* d_out, int out_size, void* d_ws, size_t ws_size,
                              hipStream_t stream) {
  (void)in_sizes; (void)n_in; (void)out_size; (void)ws_size;
  const float* fm     = (const float*)d_in[0];
  const float* amap   = (const float*)d_in[1];
  const float* conv_w = (const float*)d_in[3];
  const float* conv_b = (const float*)d_in[4];
  const float* cls_w  = (const float*)d_in[5];
  const float* cls_b  = (const float*)d_in[6];
  const float* box_w  = (const float*)d_in[7];
  const float* box_b  = (const float*)d_in[8];
  const float* fc1_w  = (const float*)d_in[9];
  const float* fc1_b  = (const float*)d_in[10];
  const float* fc2_w  = (const float*)d_in[11];
  const float* fc2_b  = (const float*)d_in[12];
  const float* cw     = (const float*)d_in[13];
  const float* cbias  = (const float*)d_in[14];
  const float* rw     = (const float*)d_in[15];
  const float* rbias  = (const float*)d_in[16];

  float* out_s = (float*)d_out;           // 36864
  float* out_d = out_s + 36864;           // 147456
  float* out_p = out_d + 147456;          // 1200
  float* out_c = out_p + 1200;            // 6300
  float* out_r = out_c + 6300;            // 24000

  char* ws = (char*)d_ws;
  // Overlay: ypart [0, 33,554,432) lives only conv2 -> rpn1x1. Everything
  // below offset 33.5MB that is written AFTER rpn1x1 may reuse that space.
  float* ypart = (float*)(ws + 0);                          // 4 x 8,388,608
  u64*   mask  = (u64*)  (ws + 0);                          // 4,512,000 (post-rpn1x1)
  unsigned short* pooled = (unsigned short*)(ws + 4718592); // 16,056,320 -> ends 20,774,912
  float* boxes = (float*)(ws + 20971520);                   // 589,824 -> 21,561,344
  u64*   keys  = (u64*)  (ws + 21561344);                   // 524,288 -> 22,085,632
  float* bx    = (float*)(ws + 22085632);                   // 96,000 -> 22,181,632
  int*   sel   = (int*)  (ws + 22181632);                   // 1,280
  float* rois  = (float*)(ws + 22182912);                   // 4,800
  float* h1pre = (float*)(ws + 22282240);                   // 5,242,880 -> 27,525,120
  unsigned short* h1bf = (unsigned short*)(ws + 27525120);  // 2,621,440 -> 30,146,560
  float* h2pre = h1pre;                                     // alias (re-zeroed mid-stream)
  unsigned short* h2bf = (unsigned short*)(ws + 30146560);  // 2,621,440 -> 32,768,000

  k_conv2<<<256, 256, 0, stream>>>(fm, conv_w, ypart);
  k_rpn1x1<<<256, 256, 0, stream>>>(ypart, conv_b, cls_w, cls_b, box_w, box_b, out_s, out_d);
  k_decode<<<256, 256, 0, stream>>>(out_s, out_d, amap, boxes, keys);

  k_sort_local<<<8, 1024, 0, stream>>>(keys);
  for (int k = 16384; k <= 65536; k <<= 1) {
    for (int j = k >> 1; j >= 8192; j >>= 1)
      k_sort_global<<<128, 256, 0, stream>>>(keys, k, j);
    k_sort_merge<<<8, 1024, 0, stream>>>(keys, k);
  }

  k_gather_sorted<<<24, 256, 0, stream>>>(keys, boxes, bx);
  k_nms_mask<<<6000, 128, 0, stream>>>(bx, mask);
  k_nms_scan<<<1, 64, 0, stream>>>(mask, sel);
  k_gather_prop<<<5, 64, 0, stream>>>(sel, bx, out_p, rois);

  // These live inside the ypart overlay region -> must run after rpn1x1.
  hipMemsetAsync((char*)pooled + (size_t)300 * 25088 * 2, 0, (size_t)20 * 25088 * 2, stream);
  hipMemsetAsync(h1pre, 0, (size_t)320 * 4096 * 4, stream);

  k_roipool<<<300 * 98, 256, 0, stream>>>(fm, rois, pooled);

  k_gemm<<<dim3(32, 8), 512, 0, stream>>>(pooled, fc1_w, h1pre, 25088, 3136, 4096);
  k_bias_relu_bf<<<5120, 256, 0, stream>>>(h1pre, fc1_b, h1bf);
  hipMemsetAsync(h2pre, 0, (size_t)320 * 4096 * 4, stream);
  k_gemm<<<dim3(32, 8), 512, 0, stream>>>(h1bf, fc2_w, h2pre, 4096, 512, 4096);
  k_bias_relu_bf<<<5120, 256, 0, stream>>>(h2pre, fc2_b, h2bf);
  k_head<<<300, 128, 0, stream>>>(h2bf, cw, cbias, rw, rbias, out_c, out_r);
}

// Round 5
// 1077.393 us; speedup vs baseline: 2.1229x; 1.0847x over previous
//
#include <hip/hip_runtime.h>
#include <stdint.h>

typedef float f32x4 __attribute__((ext_vector_type(4)));
typedef short s16x8 __attribute__((ext_vector_type(8)));
typedef unsigned long long u64;

__device__ __forceinline__ unsigned short f2bf(float f) {
  union { float f; unsigned u; } v; v.f = f;
  unsigned u = v.u;
  return (unsigned short)((u + 0x7FFFu + ((u >> 16) & 1u)) >> 16);
}
__device__ __forceinline__ float bf2f(unsigned short b) {
  union { unsigned u; float f; } v; v.u = ((unsigned)b) << 16; return v.f;
}

// ---------------- conv3: 3x3, 512->512, 64x64, SAME, K-split x4 --------------
// Block: 64 oc x (16h x 16w) px, one K-slice of 128 ic. Grid 512 = 2 blocks/CU.
// Thread: 8 oc x 1 row x 8 cols. Partial sums to ypart[s]; epilogue in rpn1x1.
#define CONV_ICC 8
__global__ __launch_bounds__(256, 2) void k_conv3(const float* __restrict__ fm,
                                                  const float* __restrict__ w,
                                                  float* __restrict__ ypart) {
  __shared__ float Xs[CONV_ICC * 342];     // [ic][18 rows][pitch 19]
  __shared__ float Ws[CONV_ICC * 9 * 64];  // [ic][k][oc]
  int bid = blockIdx.x;
  int s = bid & 3, ocg = (bid >> 2) & 7, sp = bid >> 5;   // sp 0..15
  int h0 = (sp >> 2) * 16, w0 = (sp & 3) * 16;
  int oc0 = ocg * 64;
  int t = threadIdx.x;
  int g = t >> 5, p = t & 31;
  int row = p >> 1, colb = (p & 1) * 8;
  float acc[8][8] = {};
  int cbase = s * 128;
  for (int chunk = 0; chunk < 16; chunk++) {
    int c0 = cbase + chunk * CONV_ICC;
    // stage X: 8 ic x 18 rows x 18 cols (halo +-1), pitch 19
    for (int idx = t; idx < CONV_ICC * 324; idx += 256) {
      int ic = idx / 324, rem = idx - ic * 324;
      int r = rem / 18, cc = rem - r * 18;
      int gy = h0 + r - 1, gx = w0 + cc - 1;
      float v = 0.f;
      if ((unsigned)gy < 64u && (unsigned)gx < 64u) v = fm[(c0 + ic) * 4096 + gy * 64 + gx];
      Xs[ic * 342 + r * 19 + cc] = v;
    }
    // stage W: [ic][k][oc]
    for (int idx = t; idx < CONV_ICC * 9 * 64; idx += 256) {
      int oc = idx & 63, rest = idx >> 6;
      int ic = rest / 9, k = rest - ic * 9;
      Ws[idx] = w[(u64)(oc0 + oc) * 4608 + (c0 + ic) * 9 + k];
    }
    __syncthreads();
    for (int ic = 0; ic < CONV_ICC; ic++) {
      const float* xb = &Xs[ic * 342 + colb];
      float xr[3][10];
      #pragma unroll
      for (int r = 0; r < 3; r++)
        #pragma unroll
        for (int j = 0; j < 10; j++)
          xr[r][j] = xb[(row + r) * 19 + j];
      #pragma unroll
      for (int kh = 0; kh < 3; kh++) {
        #pragma unroll
        for (int kw = 0; kw < 3; kw++) {
          const float* wp = &Ws[(ic * 9 + kh * 3 + kw) * 64 + g * 8];
          f32x4 wa = *(const f32x4*)wp;
          f32x4 wb = *(const f32x4*)(wp + 4);
          float wv[8] = {wa.x, wa.y, wa.z, wa.w, wb.x, wb.y, wb.z, wb.w};
          #pragma unroll
          for (int o = 0; o < 8; o++) {
            #pragma unroll
            for (int j = 0; j < 8; j++) {
              acc[o][j] += wv[o] * xr[kh][kw + j];
            }
          }
        }
      }
    }
    __syncthreads();
  }
  float* yp = ypart + (u64)s * 2097152;
  #pragma unroll
  for (int j = 0; j < 8; j++) {
    int pxg = (h0 + row) * 64 + (w0 + colb + j);
    f32x4 v0, v1;
    v0.x = acc[0][j]; v0.y = acc[1][j]; v0.z = acc[2][j]; v0.w = acc[3][j];
    v1.x = acc[4][j]; v1.y = acc[5][j]; v1.z = acc[6][j]; v1.w = acc[7][j];
    f32x4* dst = (f32x4*)&yp[(u64)pxg * 512 + oc0 + g * 8];
    dst[0] = v0; dst[1] = v1;
  }
}

// --------------- 1x1 convs: sum partials + bias + relu, then dots ------------
__global__ __launch_bounds__(256) void k_rpn1x1(const float* __restrict__ ypart,
                                                const float* __restrict__ conv_b,
                                                const float* __restrict__ cw, const float* __restrict__ cb,
                                                const float* __restrict__ bw, const float* __restrict__ bb,
                                                float* __restrict__ out_s, float* __restrict__ out_d) {
  __shared__ float Ys[16 * 516];
  int px0 = blockIdx.x * 16;
  int t = threadIdx.x;
  for (int c = t; c < 16 * 128; c += 256) {
    int p = c >> 7, seg = c & 127;
    u64 off = (u64)(px0 + p) * 512 + seg * 4;
    f32x4 v0 = *(const f32x4*)&ypart[off];
    f32x4 v1 = *(const f32x4*)&ypart[2097152 + off];
    f32x4 v2 = *(const f32x4*)&ypart[2 * 2097152 + off];
    f32x4 v3 = *(const f32x4*)&ypart[3 * (u64)2097152 + off];
    f32x4 b = *(const f32x4*)&conv_b[seg * 4];
    f32x4 r;
    r.x = fmaxf(v0.x + v1.x + v2.x + v3.x + b.x, 0.f);
    r.y = fmaxf(v0.y + v1.y + v2.y + v3.y + b.y, 0.f);
    r.z = fmaxf(v0.z + v1.z + v2.z + v3.z + b.z, 0.f);
    r.w = fmaxf(v0.w + v1.w + v2.w + v3.w + b.w, 0.f);
    *(f32x4*)&Ys[p * 516 + seg * 4] = r;
  }
  __syncthreads();
  int px = t & 15, og = t >> 4;
  const float* yr = &Ys[px * 516];
  for (int n = og; n < 45; n += 16) {
    const float* wr = (n < 9) ? &cw[n * 512] : &bw[(n - 9) * 512];
    float acc = 0.f;
    for (int k = 0; k < 512; k += 4) {
      f32x4 wv = *(const f32x4*)&wr[k];
      acc += wv.x * yr[k] + wv.y * yr[k + 1] + wv.z * yr[k + 2] + wv.w * yr[k + 3];
    }
    int gpx = px0 + px;
    if (n < 9) {
      float s = acc + cb[n];
      out_s[gpx * 9 + n] = 1.f / (1.f + expf(-s));
    } else {
      out_d[gpx * 36 + (n - 9)] = acc + bb[n - 9];
    }
  }
}

// --------------- box decode + sort keys --------------------------------------
__global__ void k_decode(const float* __restrict__ sc, const float* __restrict__ dl,
                         const float* __restrict__ amap,
                         float* __restrict__ boxes, u64* __restrict__ keys) {
  int i = blockIdx.x * 256 + threadIdx.x;
  if (i >= 65536) return;
  if (i < 36864) {
    int px = i / 9, a = i - px * 9;
    const float* A = &amap[i * 4];
    const float* D = &dl[px * 36 + a * 4];
    float cy = A[0] + D[0] * A[2];
    float cx = A[1] + D[1] * A[3];
    float hh = A[2] * expf(D[2]);
    float ww = A[3] * expf(D[3]);
    float y1 = fminf(fmaxf(cy - 0.5f * hh, 0.f), 1023.f);
    float x1 = fminf(fmaxf(cx - 0.5f * ww, 0.f), 1023.f);
    float y2 = fminf(fmaxf(cy + 0.5f * hh, 0.f), 1023.f);
    float x2 = fminf(fmaxf(cx + 0.5f * ww, 0.f), 1023.f);
    f32x4 v; v.x = y1; v.y = x1; v.z = y2; v.w = x2;
    *(f32x4*)&boxes[i * 4] = v;
    unsigned bits = __float_as_uint(sc[i]);
    u64 key = ((u64)bits << 16) | (u64)(0xFFFFu - (unsigned)i);
    keys[i] = ~key;  // ascending sort of ~key == descending by (score, -idx)
  } else {
    keys[i] = ~0ull;
  }
}

// --------------- bitonic sort of 65536 u64 keys (ascending) ------------------
__global__ __launch_bounds__(1024) void k_sort_local(u64* __restrict__ keys) {
  __shared__ u64 S[8192];
  int base = blockIdx.x * 8192;
  for (int i = threadIdx.x; i < 8192; i += 1024) S[i] = keys[base + i];
  __syncthreads();
  for (int k = 2; k <= 8192; k <<= 1) {
    for (int j = k >> 1; j > 0; j >>= 1) {
      for (int p = threadIdx.x; p < 4096; p += 1024) {
        int i = ((p & ~(j - 1)) << 1) | (p & (j - 1));
        int ix = i | j;
        bool up = (((base + i) & k) == 0);
        u64 a = S[i], c = S[ix];
        if ((a > c) == up) { S[i] = c; S[ix] = a; }
      }
      __syncthreads();
    }
  }
  for (int i = threadIdx.x; i < 8192; i += 1024) keys[base + i] = S[i];
}

__global__ void k_sort_global(u64* __restrict__ keys, int k, int j) {
  int p = blockIdx.x * 256 + threadIdx.x;
  int i = ((p & ~(j - 1)) << 1) | (p & (j - 1));
  int ix = i | j;
  bool up = ((i & k) == 0);
  u64 a = keys[i], c = keys[ix];
  if ((a > c) == up) { keys[i] = c; keys[ix] = a; }
}

__global__ __launch_bounds__(1024) void k_sort_merge(u64* __restrict__ keys, int k) {
  __shared__ u64 S[8192];
  int base = blockIdx.x * 8192;
  for (int i = threadIdx.x; i < 8192; i += 1024) S[i] = keys[base + i];
  __syncthreads();
  for (int j = 4096; j > 0; j >>= 1) {
    for (int p = threadIdx.x; p < 4096; p += 1024) {
      int i = ((p & ~(j - 1)) << 1) | (p & (j - 1));
      int ix = i | j;
      bool up = (((base + i) & k) == 0);
      u64 a = S[i], c = S[ix];
      if ((a > c) == up) { S[i] = c; S[ix] = a; }
    }
    __syncthreads();
  }
  for (int i = threadIdx.x; i < 8192; i += 1024) keys[base + i] = S[i];
}

__global__ void k_gather_sorted(const u64* __restrict__ keys, const float* __restrict__ boxes,
                                float* __restrict__ bx) {
  int p = blockIdx.x * 256 + threadIdx.x;
  if (p >= 6000) return;
  u64 key = ~keys[p];
  int idx = 0xFFFF - (int)(key & 0xFFFFull);
  *(f32x4*)&bx[p * 4] = *(const f32x4*)&boxes[idx * 4];
}

// --------------- NMS: suppression bitmask + sequential scan ------------------
__global__ __launch_bounds__(128) void k_nms_mask(const float* __restrict__ bx, u64* __restrict__ mask) {
  int i = blockIdx.x;
  int w = threadIdx.x;
  if (w >= 94) return;
  f32x4 bi = *(const f32x4*)&bx[i * 4];
  float ai = (bi.z - bi.x) * (bi.w - bi.y);
  u64 m = 0;
  int j0 = w * 64;
  for (int b = 0; b < 64; b++) {
    int j = j0 + b;
    if (j >= 6000) break;
    if (j <= i) continue;
    f32x4 bj = *(const f32x4*)&bx[j * 4];
    float yy1 = fmaxf(bi.x, bj.x), xx1 = fmaxf(bi.y, bj.y);
    float yy2 = fminf(bi.z, bj.z), xx2 = fminf(bi.w, bj.w);
    float inter = fmaxf(yy2 - yy1, 0.f) * fmaxf(xx2 - xx1, 0.f);
    float aj = (bj.z - bj.x) * (bj.w - bj.y);
    float iou = inter / (ai + aj - inter + 1e-8f);
    if (iou > 0.7f) m |= (1ull << b);
  }
  mask[i * 94 + w] = m;
}

// Sequential greedy scan with EARLY EXIT (see R1 notes): stops once 300
// keepers are found; fallback fills from suppressed set in index order.
__global__ __launch_bounds__(64) void k_nms_scan(const u64* __restrict__ mask, int* __restrict__ sel) {
  int lane = threadIdx.x;
  u64 rem0 = 0, rem1 = 0;
  int nkeep = 0;
  u64 cur0[16], cur1[16], nxt0[16], nxt1[16];
  bool l30 = (lane < 30);
  #pragma unroll
  for (int r = 0; r < 16; r++) {
    cur0[r] = mask[r * 94 + lane];
    cur1[r] = l30 ? mask[r * 94 + 64 + lane] : 0ull;
  }
  for (int c0 = 0; c0 < 6000; c0 += 16) {
    int n0 = c0 + 16;
    if (n0 < 6000) {
      #pragma unroll
      for (int r = 0; r < 16; r++) {
        nxt0[r] = mask[(n0 + r) * 94 + lane];
        nxt1[r] = l30 ? mask[(n0 + r) * 94 + 64 + lane] : 0ull;
      }
    }
    #pragma unroll
    for (int r = 0; r < 16; r++) {
      int i = c0 + r;
      int wi = i >> 6, bi = i & 63;
      u64 wv = (wi < 64) ? __shfl(rem0, wi, 64) : __shfl(rem1, wi - 64, 64);
      if (!((wv >> bi) & 1ull)) {
        if (lane == 0 && nkeep < 300) sel[nkeep] = i;
        nkeep++;
        rem0 |= cur0[r]; rem1 |= cur1[r];
      }
    }
    if (nkeep >= 300) return;
    #pragma unroll
    for (int r = 0; r < 16; r++) { cur0[r] = nxt0[r]; cur1[r] = nxt1[r]; }
  }
  __shared__ u64 remS[94];
  remS[lane] = rem0;
  if (l30) remS[64 + lane] = rem1;
  __syncthreads();
  if (lane == 0) {
    int k = nkeep;
    for (int i = 0; i < 6000 && k < 300; i++) {
      if ((remS[i >> 6] >> (i & 63)) & 1ull) sel[k++] = i;
    }
  }
}

__global__ void k_gather_prop(const int* __restrict__ sel, const float* __restrict__ bx,
                              float* __restrict__ out_p, float* __restrict__ rois) {
  int r = blockIdx.x * 64 + threadIdx.x;
  if (r >= 300) return;
  int p = sel[r];
  float y1 = bx[p * 4 + 0], x1 = bx[p * 4 + 1], y2 = bx[p * 4 + 2], x2 = bx[p * 4 + 3];
  out_p[r * 4 + 0] = y1; out_p[r * 4 + 1] = x1; out_p[r * 4 + 2] = y2; out_p[r * 4 + 3] = x2;
  rois[r * 4 + 0] = x1; rois[r * 4 + 1] = y1; rois[r * 4 + 2] = x2; rois[r * 4 + 3] = y2;
}

// --------------- ROI max-pool 7x7 (exact ref semantics), out bf16 ------------
__global__ __launch_bounds__(256) void k_roipool(const float* __restrict__ fm,
                                                 const float* __restrict__ rois,
                                                 unsigned short* __restrict__ pooled) {
  int roi = blockIdx.x / 98;
  int seg = blockIdx.x - roi * 98;
  __shared__ int hs[7], he[7], wls[7], wle[7];
  if (threadIdx.x < 28) {
    int kind = threadIdx.x / 7, p = threadIdx.x - kind * 7;
    float x1 = rintf(rois[roi * 4 + 0] * 0.0625f);
    float y1 = rintf(rois[roi * 4 + 1] * 0.0625f);
    float x2 = rintf(rois[roi * 4 + 2] * 0.0625f);
    float y2 = rintf(rois[roi * 4 + 3] * 0.0625f);
    float rw = fmaxf(x2 - x1 + 1.f, 1.f), rh = fmaxf(y2 - y1 + 1.f, 1.f);
    float bh = rh / 7.f, bw = rw / 7.f;
    float fp = (float)p;
    if (kind == 0) hs[p]  = (int)fminf(fmaxf(floorf(fp * bh) + y1, 0.f), 64.f);
    if (kind == 1) he[p]  = (int)fminf(fmaxf(ceilf((fp + 1.f) * bh) + y1, 0.f), 64.f);
    if (kind == 2) wls[p] = (int)fminf(fmaxf(floorf(fp * bw) + x1, 0.f), 64.f);
    if (kind == 3) wle[p] = (int)fminf(fmaxf(ceilf((fp + 1.f) * bw) + x1, 0.f), 64.f);
  }
  __syncthreads();
  int o = seg * 256 + threadIdx.x;  // < 25088
  int c = o / 49; int cell = o - c * 49;
  int ph = cell / 7, pw = cell - ph * 7;
  int y0 = hs[ph], y1e = he[ph], x0 = wls[pw], x1e = wle[pw];
  bool any = (y1e > y0) && (x1e > x0);
  float m = -1e30f;
  const float* base = &fm[c * 4096];
  for (int yy = y0; yy < y1e; yy++)
    for (int xx = x0; xx < x1e; xx++)
      m = fmaxf(m, base[yy * 64 + xx]);
  pooled[(u64)roi * 25088 + o] = f2bf(any ? m : 0.f);
}

// --------------- big GEMM: C[320][N] += A_bf16[320][K] * B_f32[N][K]^T --------
__global__ __launch_bounds__(512) void k_gemm(const unsigned short* __restrict__ A,
                                              const float* __restrict__ B,
                                              float* __restrict__ Cpre,
                                              int K, int Kslice, int N) {
  __shared__ unsigned short As[320 * 40];
  int n0 = blockIdx.x * 128;
  int s = blockIdx.y;
  int t = threadIdx.x;
  int wave = t >> 6, lane = t & 63;
  int mg = wave & 1, ng = wave >> 1;
  int m0 = mg * 160;
  int n0w = n0 + ng * 32;
  int lr = lane & 15, lk = lane >> 4;
  f32x4 acc[10][2];
  #pragma unroll
  for (int mt = 0; mt < 10; mt++)
    for (int nt = 0; nt < 2; nt++) { acc[mt][nt].x = 0; acc[mt][nt].y = 0; acc[mt][nt].z = 0; acc[mt][nt].w = 0; }
  int kbeg = s * Kslice, kend = kbeg + Kslice;
  for (int k0 = kbeg; k0 < kend; k0 += 32) {
    for (int c = t; c < 1280; c += 512) {
      int m = c >> 2, seg = (c & 3) * 8;
      *(uint4*)&As[m * 40 + seg] = *(const uint4*)&A[(u64)m * K + k0 + seg];
    }
    __syncthreads();
    s16x8 bfrag[2];
    #pragma unroll
    for (int nt = 0; nt < 2; nt++) {
      const float* bp = &B[(u64)(n0w + nt * 16 + lr) * K + k0 + lk * 8];
      f32x4 b0 = *(const f32x4*)bp;
      f32x4 b1 = *(const f32x4*)(bp + 4);
      s16x8 f;
      f[0] = (short)f2bf(b0.x); f[1] = (short)f2bf(b0.y); f[2] = (short)f2bf(b0.z); f[3] = (short)f2bf(b0.w);
      f[4] = (short)f2bf(b1.x); f[5] = (short)f2bf(b1.y); f[6] = (short)f2bf(b1.z); f[7] = (short)f2bf(b1.w);
      bfrag[nt] = f;
    }
    #pragma unroll
    for (int mt = 0; mt < 10; mt++) {
      s16x8 afrag = *(const s16x8*)&As[(m0 + mt * 16 + lr) * 40 + lk * 8];
      acc[mt][0] = __builtin_amdgcn_mfma_f32_16x16x32_bf16(afrag, bfrag[0], acc[mt][0], 0, 0, 0);
      acc[mt][1] = __builtin_amdgcn_mfma_f32_16x16x32_bf16(afrag, bfrag[1], acc[mt][1], 0, 0, 0);
    }
    __syncthreads();
  }
  #pragma unroll
  for (int mt = 0; mt < 10; mt++)
    for (int nt = 0; nt < 2; nt++)
      for (int r = 0; r < 4; r++) {
        int m = m0 + mt * 16 + lk * 4 + r;
        int n = n0w + nt * 16 + lr;
        atomicAdd(&Cpre[(u64)m * N + n], acc[mt][nt][r]);
      }
}

__global__ void k_bias_relu_bf(const float* __restrict__ pre, const float* __restrict__ bias,
                               unsigned short* __restrict__ outb) {
  int i = blockIdx.x * 256 + threadIdx.x;  // 320*4096 total
  float v = pre[i] + bias[i & 4095];
  outb[i] = f2bf(fmaxf(v, 0.f));
}

// --------------- heads: cls softmax + reg ------------------------------------
__global__ __launch_bounds__(128) void k_head(const unsigned short* __restrict__ h2,
                                              const float* __restrict__ cw, const float* __restrict__ cb,
                                              const float* __restrict__ rw, const float* __restrict__ rb,
                                              float* __restrict__ out_cls, float* __restrict__ out_reg) {
  __shared__ float Hs[4096];
  __shared__ float logits[101];
  __shared__ float es[21];
  int r = blockIdx.x, t = threadIdx.x;
  for (int c = t; c < 512; c += 128) {
    uint4 raw = *(const uint4*)&h2[(u64)r * 4096 + c * 8];
    unsigned short* sp = (unsigned short*)&raw;
    #pragma unroll
    for (int q = 0; q < 8; q++) Hs[c * 8 + q] = bf2f(sp[q]);
  }
  __syncthreads();
  for (int n = t; n < 101; n += 128) {
    const float* wrow = (n < 21) ? &cw[n * 4096] : &rw[(n - 21) * 4096];
    float acc = 0.f;
    for (int k = 0; k < 4096; k += 4) {
      f32x4 wv = *(const f32x4*)&wrow[k];
      acc += wv.x * Hs[k] + wv.y * Hs[k + 1] + wv.z * Hs[k + 2] + wv.w * Hs[k + 3];
    }
    acc += (n < 21) ? cb[n] : rb[n - 21];
    logits[n] = acc;
  }
  __syncthreads();
  if (t < 21) {
    float mx = logits[0];
    for (int q = 1; q < 21; q++) mx = fmaxf(mx, logits[q]);
    es[t] = expf(logits[t] - mx);
  }
  __syncthreads();
  if (t < 21) {
    float sum = 0.f;
    for (int q = 0; q < 21; q++) sum += es[q];
    out_cls[r * 21 + t] = es[t] / sum;
  }
  if (t >= 21 && t < 101) out_reg[r * 80 + (t - 21)] = logits[t];
}

// ------------------------------- launcher ------------------------------------
extern "C" void kernel_launch(void* const* d_in, const int* in_sizes, int n_in,
                              void* d_out, int out_size, void* d_ws, size_t ws_size,
                              hipStream_t stream) {
  (void)in_sizes; (void)n_in; (void)out_size; (void)ws_size;
  const float* fm     = (const float*)d_in[0];
  const float* amap   = (const float*)d_in[1];
  const float* conv_w = (const float*)d_in[3];
  const float* conv_b = (const float*)d_in[4];
  const float* cls_w  = (const float*)d_in[5];
  const float* cls_b  = (const float*)d_in[6];
  const float* box_w  = (const float*)d_in[7];
  const float* box_b  = (const float*)d_in[8];
  const float* fc1_w  = (const float*)d_in[9];
  const float* fc1_b  = (const float*)d_in[10];
  const float* fc2_w  = (const float*)d_in[11];
  const float* fc2_b  = (const float*)d_in[12];
  const float* cw     = (const float*)d_in[13];
  const float* cbias  = (const float*)d_in[14];
  const float* rw     = (const float*)d_in[15];
  const float* rbias  = (const float*)d_in[16];

  float* out_s = (float*)d_out;           // 36864
  float* out_d = out_s + 36864;           // 147456
  float* out_p = out_d + 147456;          // 1200
  float* out_c = out_p + 1200;            // 6300
  float* out_r = out_c + 6300;            // 24000

  char* ws = (char*)d_ws;
  // Overlay: ypart [0, 33,554,432) lives only conv3 -> rpn1x1. Everything
  // below offset 33.5MB that is written AFTER rpn1x1 may reuse that space.
  float* ypart = (float*)(ws + 0);                          // 4 x 8,388,608
  u64*   mask  = (u64*)  (ws + 0);                          // 4,512,000 (post-rpn1x1)
  unsigned short* pooled = (unsigned short*)(ws + 4718592); // 16,056,320 -> ends 20,774,912
  float* boxes = (float*)(ws + 20971520);                   // 589,824 -> 21,561,344
  u64*   keys  = (u64*)  (ws + 21561344);                   // 524,288 -> 22,085,632
  float* bx    = (float*)(ws + 22085632);                   // 96,000 -> 22,181,632
  int*   sel   = (int*)  (ws + 22181632);                   // 1,280
  float* rois  = (float*)(ws + 22182912);                   // 4,800
  float* h1pre = (float*)(ws + 22282240);                   // 5,242,880 -> 27,525,120
  unsigned short* h1bf = (unsigned short*)(ws + 27525120);  // 2,621,440 -> 30,146,560
  float* h2pre = h1pre;                                     // alias (re-zeroed mid-stream)
  unsigned short* h2bf = (unsigned short*)(ws + 30146560);  // 2,621,440 -> 32,768,000

  k_conv3<<<512, 256, 0, stream>>>(fm, conv_w, ypart);
  k_rpn1x1<<<256, 256, 0, stream>>>(ypart, conv_b, cls_w, cls_b, box_w, box_b, out_s, out_d);
  k_decode<<<256, 256, 0, stream>>>(out_s, out_d, amap, boxes, keys);

  k_sort_local<<<8, 1024, 0, stream>>>(keys);
  for (int k = 16384; k <= 65536; k <<= 1) {
    for (int j = k >> 1; j >= 8192; j >>= 1)
      k_sort_global<<<128, 256, 0, stream>>>(keys, k, j);
    k_sort_merge<<<8, 1024, 0, stream>>>(keys, k);
  }

  k_gather_sorted<<<24, 256, 0, stream>>>(keys, boxes, bx);
  k_nms_mask<<<6000, 128, 0, stream>>>(bx, mask);
  k_nms_scan<<<1, 64, 0, stream>>>(mask, sel);
  k_gather_prop<<<5, 64, 0, stream>>>(sel, bx, out_p, rois);

  // These live inside the ypart overlay region -> must run after rpn1x1.
  hipMemsetAsync((char*)pooled + (size_t)300 * 25088 * 2, 0, (size_t)20 * 25088 * 2, stream);
  hipMemsetAsync(h1pre, 0, (size_t)320 * 4096 * 4, stream);

  k_roipool<<<300 * 98, 256, 0, stream>>>(fm, rois, pooled);

  k_gemm<<<dim3(32, 8), 512, 0, stream>>>(pooled, fc1_w, h1pre, 25088, 3136, 4096);
  k_bias_relu_bf<<<5120, 256, 0, stream>>>(h1pre, fc1_b, h1bf);
  hipMemsetAsync(h2pre, 0, (size_t)320 * 4096 * 4, stream);
  k_gemm<<<dim3(32, 8), 512, 0, stream>>>(h1bf, fc2_w, h2pre, 4096, 512, 4096);
  k_bias_relu_bf<<<5120, 256, 0, stream>>>(h2pre, fc2_b, h2bf);
  k_head<<<300, 128, 0, stream>>>(h2bf, cw, cbias, rw, rbias, out_c, out_r);
}